// Round 9
// baseline (500.494 us; speedup 1.0000x reference)
//
#include <hip/hip_runtime.h>

typedef unsigned short u16;
typedef unsigned int u32;
typedef __attribute__((ext_vector_type(4))) float f32x4;
typedef __attribute__((ext_vector_type(8))) short bf16x8;
typedef __attribute__((ext_vector_type(2))) unsigned int u32x2;

#define S_LEN 2048
#define NHEAD 32
#define HDD 128
#define HID 4096
#define N_QKV 12288
#define KDIM 4096
#define RS 12288  // mixed row stride (elements)

__device__ __forceinline__ u16 f2bf(float f) {
  u32 u = __builtin_bit_cast(u32, f);
  u = (u + 0x7FFFu + ((u >> 16) & 1u)) >> 16;
  return (u16)u;
}
__device__ __forceinline__ float bf2f(u16 h) {
  u32 u = ((u32)h) << 16;
  return __builtin_bit_cast(float, u);
}

__device__ __forceinline__ void gl2lds16(const void* g, void* l) {
  __builtin_amdgcn_global_load_lds(
      (const __attribute__((address_space(1))) u32*)g,
      (__attribute__((address_space(3))) u32*)l, 16, 0, 0);
}

#define FULL_BAR()                          \
  {                                         \
    asm volatile("" ::: "memory");          \
    __builtin_amdgcn_s_barrier();           \
    asm volatile("" ::: "memory");          \
  }

// ------ fused fp32 -> bf16 conversion (3 tensors) + RoPE trig tables ------
__global__ __launch_bounds__(256) void cvt3_kernel(const float* __restrict__ s0, u16* __restrict__ d0, int n0,
                                                   const float* __restrict__ s1, u16* __restrict__ d1, int n1,
                                                   const float* __restrict__ s2, u16* __restrict__ d2, int n2,
                                                   float* __restrict__ cos_t, float* __restrict__ sin_t) {
  int i = blockIdx.x * blockDim.x + threadIdx.x;
  // trig tables: first 65536 threads
  if (i < S_LEN * 32) {
    int s = i >> 5, ii = i & 31;
    float invf = expf(-0.28782313662425572f * (float)ii);
    float a = (float)s * invf;
    cos_t[i] = cosf(a);
    sin_t[i] = sinf(a);
  }
  int st = gridDim.x * blockDim.x;
  int ntot = n0 + n1 + n2;
  for (; i < ntot; i += st) {
    const float* s;
    u16* d;
    int j = i;
    if (j < n0) {
      s = s0; d = d0;
    } else if (j < n0 + n1) {
      j -= n0; s = s1; d = d1;
    } else {
      j -= n0 + n1; s = s2; d = d2;
    }
    float4 v = ((const float4*)s)[j];
    u32x2 o;
    o.x = (u32)f2bf(v.x) | ((u32)f2bf(v.y) << 16);
    o.y = (u32)f2bf(v.z) | ((u32)f2bf(v.w) << 16);
    ((u32x2*)d)[j] = o;
  }
}

// ---------------- 2D RoPE in-place on mixed [s][12288] --------------------
__global__ __launch_bounds__(256) void rope_kernel(u16* __restrict__ mixed,
                                                   const int* __restrict__ pid,
                                                   const float* __restrict__ cos_t,
                                                   const float* __restrict__ sin_t) {
  int idx = blockIdx.x * blockDim.x + threadIdx.x;
  const int total = 2 * NHEAD * S_LEN * 2 * 8;  // 2^21
  if (idx >= total) return;
  int j = idx & 7;
  int half = (idx >> 3) & 1;
  int s = (idx >> 4) & (S_LEN - 1);
  int h = (idx >> 15) & (NHEAD - 1);
  int qk = idx >> 20;
  int i0 = j * 4;
  int p = pid[half * S_LEN + s];
  float4 c4 = *(const float4*)(cos_t + p * 32 + i0);
  float4 s4 = *(const float4*)(sin_t + p * 32 + i0);
  u16* base = mixed + (size_t)s * RS + h * 384 + qk * 128 + half * 64 + i0;
  ushort4 x1v = *(const ushort4*)(base);
  ushort4 x2v = *(const ushort4*)(base + 32);
  float sc = qk ? 1.0f : 0.08838834764831845f;
  ushort4 o1, o2;
  {
    float x1 = bf2f(x1v.x), x2 = bf2f(x2v.x);
    o1.x = f2bf((x1 * c4.x - x2 * s4.x) * sc);
    o2.x = f2bf((x2 * c4.x + x1 * s4.x) * sc);
  }
  {
    float x1 = bf2f(x1v.y), x2 = bf2f(x2v.y);
    o1.y = f2bf((x1 * c4.y - x2 * s4.y) * sc);
    o2.y = f2bf((x2 * c4.y + x1 * s4.y) * sc);
  }
  {
    float x1 = bf2f(x1v.z), x2 = bf2f(x2v.z);
    o1.z = f2bf((x1 * c4.z - x2 * s4.z) * sc);
    o2.z = f2bf((x2 * c4.z + x1 * s4.z) * sc);
  }
  {
    float x1 = bf2f(x1v.w), x2 = bf2f(x2v.w);
    o1.w = f2bf((x1 * c4.w - x2 * s4.w) * sc);
    o2.w = f2bf((x2 * c4.w + x1 * s4.w) * sc);
  }
  *(ushort4*)(base) = o1;
  *(ushort4*)(base + 32) = o2;
}

// -------- 256 x (32*NW) bf16 GEMM, BK=64, 4M x 2N waves, 2 phases/tile ----
// C = A * B^T (+bias).  A:[M][4096] bf16, B:[N][4096] bf16 (K contiguous).
// 512 thr = 8 waves as 4M x 2N; per-wave 64 x 16*NW; acc[4][NW].
// LDS = A0(16K) | A1(16K) | B(2 kk-subunits, BN*64 B each); ring-2.
// Per tile TWO phases (1 barrier each — R4..R8 record shows barrier count
// per tile is the live variable: 8 bar = 33-37%, 4 bar = 41.5%):
//   ph0: read a(kk0)+b(kk0) | ISSUE A0(kt+1)+B(kt+1) | vmcnt(2+NLB) | BAR | 4*NW MFMA
//   ph1: read a(kk1)+b(kk1) | ISSUE A1(kt+1)         | vmcnt(2)     | BAR | 4*NW MFMA
// Ledger: A0/B(t) certified at ph1(t-1) [vmcnt(2): only A1(t) after them];
// A1(t) certified at ph0(t) [vmcnt(2+NLB): A0(t+1)+B(t+1) after it].
// Queue never drains below 2 mid-loop. Paired-row swizzle (line=row>>1,
// slot ^= line&7): 0 bank conflicts since R3.
template <int NW, int EPI>
__global__ __launch_bounds__(512, 2) void gemmK(const u16* __restrict__ A,
                                                const u16* __restrict__ B,
                                                const float* __restrict__ bias, int N, int NTt,
                                                u16* __restrict__ outb, float* __restrict__ outf) {
  constexpr int BN = 32 * NW;
  constexpr int NLB = NW / 2;              // B staging loads per thread
  constexpr int BSUB = BN * 64;            // bytes per B kk-subunit
  constexpr int BUFSZ = 32768 + 2 * BSUB;
  __shared__ __align__(16) char lds[2][BUFSZ];

  const int tid = threadIdx.x;
  const int lane = tid & 63, w = tid >> 6;
  const int l15 = lane & 15, g = lane >> 4;
  const int wm = w >> 1, wn = w & 1;  // 4M x 2N wave grid

  // bijective XCD swizzle (gridDim.x = 8*perx, perx = 8*npx), M-fastest
  int perx = gridDim.x >> 3;
  int npx = perx >> 3;
  int x = blockIdx.x & 7, loc = blockIdx.x >> 3;
  int mb = loc & 7, nb = x * npx + (loc >> 3);
  const int bm = mb * 256, bn = nb * BN;

  f32x4 acc[4][NW];
  f32x4 z4 = {0.f, 0.f, 0.f, 0.f};
#pragma unroll
  for (int mi = 0; mi < 4; ++mi)
#pragma unroll
    for (int ni = 0; ni < NW; ++ni) acc[mi][ni] = z4;

  const size_t K2 = (size_t)KDIM * 2;

  // ---- A staging map (per kk-subunit: 256 rows x 64B, paired-row swizzle)
  const char* gA[2];
#pragma unroll
  for (int j = 0; j < 2; ++j) {
    int slot = j * 512 + tid;
    int line = slot >> 3;
    int sl = (slot & 7) ^ (line & 7);
    int row = 2 * line + (sl >> 2);
    int colb = (sl & 3) * 16;
    gA[j] = (const char*)A + (size_t)(bm + row) * K2 + colb;
  }
  // ---- B staging map (2 kk-subunits of BN rows x 64B, same swizzle)
  const char* gB[NLB];
#pragma unroll
  for (int j = 0; j < NLB; ++j) {
    int n_ = j * 512 + tid;
    int kkj = (n_ >= 128 * NW) ? 1 : 0;
    int m_ = n_ - kkj * 128 * NW;
    int line = m_ >> 3;
    int sl = (m_ & 7) ^ (line & 7);
    int row = 2 * line + (sl >> 2);
    int colb = (sl & 3) * 16;
    gB[j] = (const char*)B + (size_t)(bn + row) * K2 + kkj * 64 + colb;
  }
  const int ldst = w * 1024;

#define ISSUE_A(t, kk)                                                        \
  {                                                                           \
    char* Lb = lds[(t) & 1] + (kk) * 16384;                                   \
    gl2lds16(gA[0] + (size_t)(t) * 128 + (kk) * 64, Lb + ldst);               \
    gl2lds16(gA[1] + (size_t)(t) * 128 + (kk) * 64, Lb + 8192 + ldst);        \
  }
#define ISSUE_B(t)                                                            \
  {                                                                           \
    char* Lb = lds[(t) & 1] + 32768;                                          \
    _Pragma("unroll")                                                         \
    for (int j = 0; j < NLB; ++j)                                             \
      gl2lds16(gB[j] + (size_t)(t) * 128, Lb + j * 8192 + ldst);              \
  }

  // ---- fragment ds_read byte offsets (paired-row swizzle)
  int offA[4], offB[2][NW];
#pragma unroll
  for (int mi = 0; mi < 4; ++mi) {
    int r = wm * 64 + mi * 16 + l15;
    int line = r >> 1;
    int sl = (((r & 1) << 2) + g) ^ (line & 7);
    offA[mi] = line * 128 + sl * 16;
  }
#pragma unroll
  for (int kk = 0; kk < 2; ++kk)
#pragma unroll
    for (int ni = 0; ni < NW; ++ni) {
      int r = wn * (16 * NW) + ni * 16 + l15;
      int line = r >> 1;
      int sl = (((r & 1) << 2) + g) ^ (line & 7);
      offB[kk][ni] = 32768 + kk * BSUB + line * 128 + sl * 16;
    }

  // ---- prologue: stage tile 0; certify A0(0)+B(0) (A1(0) still in flight)
  ISSUE_A(0, 0);
  ISSUE_B(0);
  ISSUE_A(0, 1);
  asm volatile("s_waitcnt vmcnt(2)" ::: "memory");
  FULL_BAR();

  for (int kt = 0; kt < NTt; ++kt) {
    const char* buf = lds[kt & 1];
    const bool pf = (kt + 1) < NTt;
    bf16x8 a[4], b[NW];
    // ---- ph0: kk0 (a 4 + b NW reads | issue A0'+B' | vmcnt | BAR | 4*NW MFMA)
#pragma unroll
    for (int mi = 0; mi < 4; ++mi) a[mi] = *(const bf16x8*)(buf + offA[mi]);
#pragma unroll
    for (int ni = 0; ni < NW; ++ni) b[ni] = *(const bf16x8*)(buf + offB[0][ni]);
    if (pf) {
      ISSUE_A(kt + 1, 0);
      ISSUE_B(kt + 1);
      asm volatile("s_waitcnt vmcnt(%0)" ::"i"(2 + NLB) : "memory");
    } else {
      asm volatile("s_waitcnt vmcnt(0)" ::: "memory");
    }
    FULL_BAR();
    __builtin_amdgcn_s_setprio(1);
#pragma unroll
    for (int mi = 0; mi < 4; ++mi)
#pragma unroll
      for (int ni = 0; ni < NW; ++ni)
        acc[mi][ni] = __builtin_amdgcn_mfma_f32_16x16x32_bf16(a[mi], b[ni], acc[mi][ni], 0, 0, 0);
    __builtin_amdgcn_s_setprio(0);
    // ---- ph1: kk1 (a 4 + b NW reads | issue A1' | vmcnt(2) | BAR | 4*NW MFMA)
#pragma unroll
    for (int mi = 0; mi < 4; ++mi) a[mi] = *(const bf16x8*)(buf + 16384 + offA[mi]);
#pragma unroll
    for (int ni = 0; ni < NW; ++ni) b[ni] = *(const bf16x8*)(buf + offB[1][ni]);
    if (pf) {
      ISSUE_A(kt + 1, 1);
      asm volatile("s_waitcnt vmcnt(2)" ::: "memory");
    }
    FULL_BAR();
    __builtin_amdgcn_s_setprio(1);
#pragma unroll
    for (int mi = 0; mi < 4; ++mi)
#pragma unroll
      for (int ni = 0; ni < NW; ++ni)
        acc[mi][ni] = __builtin_amdgcn_mfma_f32_16x16x32_bf16(a[mi], b[ni], acc[mi][ni], 0, 0, 0);
    __builtin_amdgcn_s_setprio(0);
  }
#undef ISSUE_A
#undef ISSUE_B

  // ---- epilogue: D row(M) = 4*g + reg, col(N) = l15
#pragma unroll
  for (int ni = 0; ni < NW; ++ni) {
    int n = bn + wn * (16 * NW) + ni * 16 + l15;
    float bv = bias[n];
    if (EPI == 0) {
#pragma unroll
      for (int mi = 0; mi < 4; ++mi) {
        int m0 = bm + wm * 64 + mi * 16 + 4 * g;
#pragma unroll
        for (int rr = 0; rr < 4; ++rr)
          outb[(size_t)(m0 + rr) * N + n] = f2bf(acc[mi][ni][rr] + bv);
      }
    } else {
#pragma unroll
      for (int mi = 0; mi < 4; ++mi) {
        int m0 = bm + wm * 64 + mi * 16 + 4 * g;
#pragma unroll
        for (int rr = 0; rr < 4; ++rr) outf[(size_t)(m0 + rr) * N + n] = acc[mi][ni][rr] + bv;
      }
    }
  }
}

// ---------------- flash attention: constant-work block pairs --------------
// Grid 512 = 16 pairs x 32 heads, 256 thr. Block b handles q-blocks
// (b, 31-b) in two sequential passes: work = (2b+2)+(2(31-b)+2) = 66 tiles
// EXACTLY constant per block — balance independent of block->CU mapping.
// All 512 blocks co-resident (2/CU, 22KB LDS, 8 waves/CU... 4 waves/block).
__global__ __launch_bounds__(256) void attn_kernel(const u16* __restrict__ mixed,
                                                   u16* __restrict__ ctx) {
  __shared__ __align__(16) u16 Ksh[32 * 136];
  __shared__ __align__(16) u16 Vsh[128 * 32];
  __shared__ __align__(16) u16 Pt[4][16 * 40];

  int tid = threadIdx.x;
  int lane = tid & 63, w = tid >> 6;
  int lane15 = lane & 15, g = lane >> 4;

  int bpair = blockIdx.x & 15;
  int h = blockIdx.x >> 4;

  const u16* qp = mixed + (size_t)h * 384;
  const u16* kp = mixed + (size_t)h * 384 + 128;
  const u16* vp = mixed + (size_t)h * 384 + 256;

  int krow = tid >> 3, kc = (tid & 7) * 16;
  int a_ = tid & 15, b_ = tid >> 4;
  f32x4 z4 = {0.f, 0.f, 0.f, 0.f};

  for (int pass = 0; pass < 2; ++pass) {
    int qi = pass ? (31 - bpair) : bpair;
    int qbase = qi * 64;
    int qrow = qbase + w * 16 + lane15;
    int ntiles = 2 * qi + 2;

    bf16x8 qf[4];
    const u16* qptr = qp + (size_t)qrow * RS + g * 8;
#pragma unroll
    for (int d0 = 0; d0 < 4; ++d0) qf[d0] = *(const bf16x8*)(qptr + d0 * 32);

    f32x4 pv[8];
#pragma unroll
    for (int db = 0; db < 8; ++db) pv[db] = z4;
    float m_run = -1e30f, l_run = 0.0f;

    for (int t = 0; t < ntiles; ++t) {
      int kb0 = t * 32;
      __syncthreads();
      {
        const bf16x8* src = (const bf16x8*)(kp + (size_t)(kb0 + krow) * RS + kc);
        bf16x8 x0 = src[0], x1 = src[1];
        *(bf16x8*)(Ksh + krow * 136 + kc) = x0;
        *(bf16x8*)(Ksh + krow * 136 + kc + 8) = x1;
        int k0 = 2 * a_, d0 = 8 * b_;
        bf16x8 r0 = *(const bf16x8*)(vp + (size_t)(kb0 + k0) * RS + d0);
        bf16x8 r1 = *(const bf16x8*)(vp + (size_t)(kb0 + k0 + 1) * RS + d0);
#pragma unroll
        for (int jj = 0; jj < 8; ++jj) {
          int d = d0 + jj;
          u32 val = (u32)(u16)r0[jj] | ((u32)(u16)r1[jj] << 16);
          *(u32*)(Vsh + d * 32 + (((k0 >> 3) ^ (d & 3)) << 3) + (k0 & 7)) = val;
        }
      }
      __syncthreads();

      f32x4 sa0 = z4, sa1 = z4;
#pragma unroll
      for (int d0 = 0; d0 < 4; ++d0) {
        bf16x8 k0f = *(const bf16x8*)(Ksh + lane15 * 136 + d0 * 32 + g * 8);
        bf16x8 k1f = *(const bf16x8*)(Ksh + (16 + lane15) * 136 + d0 * 32 + g * 8);
        sa0 = __builtin_amdgcn_mfma_f32_16x16x32_bf16(k0f, qf[d0], sa0, 0, 0, 0);
        sa1 = __builtin_amdgcn_mfma_f32_16x16x32_bf16(k1f, qf[d0], sa1, 0, 0, 0);
      }
      float s[8];
#pragma unroll
      for (int rr = 0; rr < 4; ++rr) {
        int kg0 = kb0 + 4 * g + rr;
        int kg1 = kb0 + 16 + 4 * g + rr;
        s[rr] = (kg0 > qrow) ? -1e30f : sa0[rr];
        s[4 + rr] = (kg1 > qrow) ? -1e30f : sa1[rr];
      }
      float mx = s[0];
#pragma unroll
      for (int i2 = 1; i2 < 8; ++i2) mx = fmaxf(mx, s[i2]);
      mx = fmaxf(mx, __shfl_xor(mx, 16));
      mx = fmaxf(mx, __shfl_xor(mx, 32));
      float mnew = fmaxf(m_run, mx);
      float fac = exp2f((m_run - mnew) * 1.4426950408889634f);
      float p[8], psum = 0.f;
#pragma unroll
      for (int i2 = 0; i2 < 8; ++i2) {
        p[i2] = exp2f((s[i2] - mnew) * 1.4426950408889634f);
        psum += p[i2];
      }
      psum += __shfl_xor(psum, 16);
      psum += __shfl_xor(psum, 32);
      l_run = l_run * fac + psum;
      m_run = mnew;
#pragma unroll
      for (int db = 0; db < 8; ++db) pv[db] *= fac;

      u32 w0 = (u32)f2bf(p[0]) | ((u32)f2bf(p[1]) << 16);
      u32 w1 = (u32)f2bf(p[2]) | ((u32)f2bf(p[3]) << 16);
      u32 w2 = (u32)f2bf(p[4]) | ((u32)f2bf(p[5]) << 16);
      u32 w3 = (u32)f2bf(p[6]) | ((u32)f2bf(p[7]) << 16);
      u32x2 pa, pb;
      pa.x = w0; pa.y = w1; pb.x = w2; pb.y = w3;
      *(u32x2*)(&Pt[w][lane15 * 40 + 4 * g]) = pa;
      *(u32x2*)(&Pt[w][lane15 * 40 + 16 + 4 * g]) = pb;
      asm volatile("s_waitcnt lgkmcnt(0)" ::: "memory");
      bf16x8 pfrag = *(const bf16x8*)(&Pt[w][lane15 * 40 + 8 * g]);

#pragma unroll
      for (int db = 0; db < 8; ++db) {
        int d = db * 16 + lane15;
        bf16x8 vf = *(const bf16x8*)(Vsh + d * 32 + ((g ^ (d & 3)) << 3));
        pv[db] = __builtin_amdgcn_mfma_f32_16x16x32_bf16(vf, pfrag, pv[db], 0, 0, 0);
      }
    }

    float inv = 1.0f / l_run;
#pragma unroll
    for (int db = 0; db < 8; ++db) {
      ushort4 o;
      o.x = f2bf(pv[db][0] * inv);
      o.y = f2bf(pv[db][1] * inv);
      o.z = f2bf(pv[db][2] * inv);
      o.w = f2bf(pv[db][3] * inv);
      *(ushort4*)(ctx + (size_t)qrow * HID + h * HDD + db * 16 + 4 * g) = o;
    }
    __syncthreads();  // LDS reuse safety across passes
  }
}

// ---------------- launcher -------------------------------------------------
extern "C" void kernel_launch(void* const* d_in, const int* in_sizes, int n_in,
                              void* d_out, int out_size, void* d_ws, size_t ws_size,
                              hipStream_t stream) {
  const float* hidden = (const float*)d_in[0];
  const int* pid = (const int*)d_in[1];
  const float* wqkv = (const float*)d_in[3];
  const float* bqkv = (const float*)d_in[4];
  const float* wdense = (const float*)d_in[5];
  const float* bdense = (const float*)d_in[6];
  float* out = (float*)d_out;

  char* ws = (char*)d_ws;
  u16* W1 = (u16*)ws;                        // [12288][4096] bf16
  u16* W2 = (u16*)(ws + 100663296);          // [4096][4096] bf16
  u16* X = (u16*)(ws + 134217728);           // [2048][4096] bf16
  u16* mixed = (u16*)(ws + 150994944);       // [2048][12288] bf16
  u16* ctx = (u16*)(ws + 201326592);         // [2048][4096] bf16
  float* cos_t = (float*)(ws + 218103808);
  float* sin_t = (float*)(ws + 218365952);

  cvt3_kernel<<<dim3(2048), dim3(256), 0, stream>>>(
      wqkv, W1, N_QKV * KDIM / 4, wdense, W2, HID * KDIM / 4, hidden, X, S_LEN * HID / 4,
      cos_t, sin_t);

  // QKV: BN=192 -> 8 M x 64 N = 512 blocks = 2.00 exact rounds
  gemmK<6, 0><<<dim3(512), dim3(512), 0, stream>>>(
      X, W1, bqkv, N_QKV, 64, mixed, nullptr);

  rope_kernel<<<dim3(8192), dim3(256), 0, stream>>>(mixed, pid, cos_t, sin_t);

  attn_kernel<<<dim3(512), dim3(256), 0, stream>>>(mixed, ctx);

  // dense: BN=128 -> 8 M x 32 N = 256 blocks = 1.00 exact round
  gemmK<4, 1><<<dim3(256), dim3(512), 0, stream>>>(
      ctx, W2, bdense, HID, 64, nullptr, out);
}

// Round 10
// 497.295 us; speedup vs baseline: 1.0064x; 1.0064x over previous
//
#include <hip/hip_runtime.h>

typedef unsigned short u16;
typedef unsigned int u32;
typedef __attribute__((ext_vector_type(4))) float f32x4;
typedef __attribute__((ext_vector_type(8))) short bf16x8;
typedef __attribute__((ext_vector_type(2))) unsigned int u32x2;

#define S_LEN 2048
#define NHEAD 32
#define HDD 128
#define HID 4096
#define N_QKV 12288
#define KDIM 4096
#define RS 12288  // mixed row stride (elements)

__device__ __forceinline__ u16 f2bf(float f) {
  u32 u = __builtin_bit_cast(u32, f);
  u = (u + 0x7FFFu + ((u >> 16) & 1u)) >> 16;
  return (u16)u;
}
__device__ __forceinline__ float bf2f(u16 h) {
  u32 u = ((u32)h) << 16;
  return __builtin_bit_cast(float, u);
}

__device__ __forceinline__ void gl2lds16(const void* g, void* l) {
  __builtin_amdgcn_global_load_lds(
      (const __attribute__((address_space(1))) u32*)g,
      (__attribute__((address_space(3))) u32*)l, 16, 0, 0);
}

#define FULL_BAR()                          \
  {                                         \
    asm volatile("" ::: "memory");          \
    __builtin_amdgcn_s_barrier();           \
    asm volatile("" ::: "memory");          \
  }

// ------ fused fp32 -> bf16 conversion (3 tensors) + RoPE trig tables ------
__global__ __launch_bounds__(256) void cvt3_kernel(const float* __restrict__ s0, u16* __restrict__ d0, int n0,
                                                   const float* __restrict__ s1, u16* __restrict__ d1, int n1,
                                                   const float* __restrict__ s2, u16* __restrict__ d2, int n2,
                                                   float* __restrict__ cos_t, float* __restrict__ sin_t) {
  int i = blockIdx.x * blockDim.x + threadIdx.x;
  if (i < S_LEN * 32) {
    int s = i >> 5, ii = i & 31;
    float invf = expf(-0.28782313662425572f * (float)ii);
    float a = (float)s * invf;
    cos_t[i] = cosf(a);
    sin_t[i] = sinf(a);
  }
  int st = gridDim.x * blockDim.x;
  int ntot = n0 + n1 + n2;
  for (; i < ntot; i += st) {
    const float* s;
    u16* d;
    int j = i;
    if (j < n0) {
      s = s0; d = d0;
    } else if (j < n0 + n1) {
      j -= n0; s = s1; d = d1;
    } else {
      j -= n0 + n1; s = s2; d = d2;
    }
    float4 v = ((const float4*)s)[j];
    u32x2 o;
    o.x = (u32)f2bf(v.x) | ((u32)f2bf(v.y) << 16);
    o.y = (u32)f2bf(v.z) | ((u32)f2bf(v.w) << 16);
    ((u32x2*)d)[j] = o;
  }
}

// -------- QKV GEMM: 256x384 tile, BK=32, ring-3 LDS, one dispatch round ---
// C = A * B^T + bias -> bf16 mixed.  A:[2048][4096], B:[12288][4096] bf16.
// 512 thr = 8 waves (2M x 4N), per-wave 128x96, acc[8][6] (192 VGPR).
// Staged-byte intensity 157 FLOP/B (vs 110 at 256x192) — attacks both the
// LDS port and L2->CU delivery, the two measured comparable costs.
// LDS ring-3 x (A 16KB | B 24KB) = 120 KB. 5 loads/thread/tile (A2+B3).
// Per tile 2 phases: ph0 {read a0-3,b0-5 | ISSUE A(t+2) | BAR | 24 MFMA},
//                    ph1 {read a4-7      | ISSUE B(t+2) | vmcnt(5) | BAR | 24 MFMA}.
// Ledger: tile t+1's A,B certified at ph1(t) vmcnt(5) (keeps A/B(t+2) in
// flight; cert lead ~3 phases >> 900cy HBM). Tail: vmcnt(0) at t=125... NTt-2.
// Paired-row swizzle (line=row>>1, slot^=line&7): 0 conflicts since R3.
__global__ __launch_bounds__(512, 2) void gemmQ(const u16* __restrict__ A,
                                                const u16* __restrict__ B,
                                                const float* __restrict__ bias,
                                                u16* __restrict__ outb) {
  __shared__ __align__(16) char lds[3][40960];

  const int tid = threadIdx.x;
  const int lane = tid & 63, w = tid >> 6;
  const int l15 = lane & 15, g = lane >> 4;
  const int wm = w >> 2, wn = w & 3;  // 2M x 4N

  // bijective XCD swizzle: 256 blocks, perx=32, npx=4, M-fastest
  int x = blockIdx.x & 7, loc = blockIdx.x >> 3;
  int mb = loc & 7, nb = x * 4 + (loc >> 3);
  const int bm = mb * 256, bn = nb * 384;

  f32x4 acc[8][6];
  f32x4 z4 = {0.f, 0.f, 0.f, 0.f};
#pragma unroll
  for (int mi = 0; mi < 8; ++mi)
#pragma unroll
    for (int ni = 0; ni < 6; ++ni) acc[mi][ni] = z4;

  const size_t K2 = (size_t)KDIM * 2;

  // A staging: 256 rows x 64B = 1024 slots, 2 loads/thread (inverse swizzle)
  const char* gA[2];
#pragma unroll
  for (int j = 0; j < 2; ++j) {
    int slot = j * 512 + tid;
    int line = slot >> 3;
    int sl = (slot & 7) ^ (line & 7);
    int row = 2 * line + (sl >> 2);
    int colb = (sl & 3) * 16;
    gA[j] = (const char*)A + (size_t)(bm + row) * K2 + colb;
  }
  // B staging: 384 rows x 64B = 1536 slots, 3 loads/thread
  const char* gB[3];
#pragma unroll
  for (int j = 0; j < 3; ++j) {
    int slot = j * 512 + tid;
    int line = slot >> 3;
    int sl = (slot & 7) ^ (line & 7);
    int row = 2 * line + (sl >> 2);
    int colb = (sl & 3) * 16;
    gB[j] = (const char*)B + (size_t)(bn + row) * K2 + colb;
  }
  const int ldst = w * 1024;

#define QIA(t, bi)                                                  \
  {                                                                 \
    char* Lb = lds[bi];                                             \
    gl2lds16(gA[0] + (size_t)(t) * 64, Lb + ldst);                  \
    gl2lds16(gA[1] + (size_t)(t) * 64, Lb + 8192 + ldst);           \
  }
#define QIB(t, bi)                                                  \
  {                                                                 \
    char* Lb = lds[bi] + 16384;                                     \
    _Pragma("unroll")                                               \
    for (int j = 0; j < 3; ++j)                                     \
      gl2lds16(gB[j] + (size_t)(t) * 64, Lb + j * 8192 + ldst);     \
  }

  // fragment ds_read byte offsets (paired-row swizzle)
  int offA[8], offB[6];
#pragma unroll
  for (int mi = 0; mi < 8; ++mi) {
    int r = wm * 128 + mi * 16 + l15;
    int line = r >> 1;
    int sl = (((r & 1) << 2) + g) ^ (line & 7);
    offA[mi] = line * 128 + sl * 16;
  }
#pragma unroll
  for (int ni = 0; ni < 6; ++ni) {
    int r = wn * 96 + ni * 16 + l15;
    int line = r >> 1;
    int sl = (((r & 1) << 2) + g) ^ (line & 7);
    offB[ni] = 16384 + line * 128 + sl * 16;
  }

  // prologue: tiles 0,1 staged; certify tile 0 (keep tile 1's 5 in flight)
  QIA(0, 0); QIB(0, 0);
  QIA(1, 1); QIB(1, 1);
  asm volatile("s_waitcnt vmcnt(5)" ::: "memory");
  FULL_BAR();

  int cur = 0, nx2 = 2;
  for (int kt = 0; kt < 128; ++kt) {
    const char* buf = lds[cur];
    const bool pf = (kt + 2) < 128;
    bf16x8 a[4], b[6];
    // ph0: a0-3 + b0-5 | ISSUE A(kt+2) | BAR | 24 MFMA
#pragma unroll
    for (int mi = 0; mi < 4; ++mi) a[mi] = *(const bf16x8*)(buf + offA[mi]);
#pragma unroll
    for (int ni = 0; ni < 6; ++ni) b[ni] = *(const bf16x8*)(buf + offB[ni]);
    if (pf) QIA(kt + 2, nx2);
    FULL_BAR();
    __builtin_amdgcn_s_setprio(1);
#pragma unroll
    for (int mi = 0; mi < 4; ++mi)
#pragma unroll
      for (int ni = 0; ni < 6; ++ni)
        acc[mi][ni] = __builtin_amdgcn_mfma_f32_16x16x32_bf16(a[mi], b[ni], acc[mi][ni], 0, 0, 0);
    __builtin_amdgcn_s_setprio(0);
    // ph1: a4-7 | ISSUE B(kt+2) | vmcnt(5) | BAR | 24 MFMA
#pragma unroll
    for (int mi = 0; mi < 4; ++mi) a[mi] = *(const bf16x8*)(buf + offA[4 + mi]);
    if (pf) {
      QIB(kt + 2, nx2);
      asm volatile("s_waitcnt vmcnt(5)" ::: "memory");
    } else if (kt == 126) {
      asm volatile("s_waitcnt vmcnt(0)" ::: "memory");
    }
    FULL_BAR();
    __builtin_amdgcn_s_setprio(1);
#pragma unroll
    for (int mi = 0; mi < 4; ++mi)
#pragma unroll
      for (int ni = 0; ni < 6; ++ni)
        acc[4 + mi][ni] = __builtin_amdgcn_mfma_f32_16x16x32_bf16(a[mi], b[ni], acc[4 + mi][ni], 0, 0, 0);
    __builtin_amdgcn_s_setprio(0);
    cur = (cur + 1 == 3) ? 0 : cur + 1;
    nx2 = (nx2 + 1 == 3) ? 0 : nx2 + 1;
  }
#undef QIA
#undef QIB

  // epilogue: D row(M) = 4*g + reg, col(N) = l15
#pragma unroll
  for (int ni = 0; ni < 6; ++ni) {
    int n = bn + wn * 96 + ni * 16 + l15;
    float bv = bias[n];
#pragma unroll
    for (int mi = 0; mi < 8; ++mi) {
      int m0 = bm + wm * 128 + mi * 16 + 4 * g;
#pragma unroll
      for (int rr = 0; rr < 4; ++rr)
        outb[(size_t)(m0 + rr) * N_QKV + n] = f2bf(acc[mi][ni][rr] + bv);
    }
  }
}

// -------- dense GEMM: 256 x (32*NW), BK=64, 4M x 2N waves, 2-phase --------
template <int NW, int EPI>
__global__ __launch_bounds__(512, 2) void gemmK(const u16* __restrict__ A,
                                                const u16* __restrict__ B,
                                                const float* __restrict__ bias, int N, int NTt,
                                                u16* __restrict__ outb, float* __restrict__ outf) {
  constexpr int BN = 32 * NW;
  constexpr int NLB = NW / 2;
  constexpr int BSUB = BN * 64;
  constexpr int BUFSZ = 32768 + 2 * BSUB;
  __shared__ __align__(16) char lds[2][BUFSZ];

  const int tid = threadIdx.x;
  const int lane = tid & 63, w = tid >> 6;
  const int l15 = lane & 15, g = lane >> 4;
  const int wm = w >> 1, wn = w & 1;

  int perx = gridDim.x >> 3;
  int npx = perx >> 3;
  int x = blockIdx.x & 7, loc = blockIdx.x >> 3;
  int mb = loc & 7, nb = x * npx + (loc >> 3);
  const int bm = mb * 256, bn = nb * BN;

  f32x4 acc[4][NW];
  f32x4 z4 = {0.f, 0.f, 0.f, 0.f};
#pragma unroll
  for (int mi = 0; mi < 4; ++mi)
#pragma unroll
    for (int ni = 0; ni < NW; ++ni) acc[mi][ni] = z4;

  const size_t K2 = (size_t)KDIM * 2;

  const char* gA[2];
#pragma unroll
  for (int j = 0; j < 2; ++j) {
    int slot = j * 512 + tid;
    int line = slot >> 3;
    int sl = (slot & 7) ^ (line & 7);
    int row = 2 * line + (sl >> 2);
    int colb = (sl & 3) * 16;
    gA[j] = (const char*)A + (size_t)(bm + row) * K2 + colb;
  }
  const char* gB[NLB];
#pragma unroll
  for (int j = 0; j < NLB; ++j) {
    int n_ = j * 512 + tid;
    int kkj = (n_ >= 128 * NW) ? 1 : 0;
    int m_ = n_ - kkj * 128 * NW;
    int line = m_ >> 3;
    int sl = (m_ & 7) ^ (line & 7);
    int row = 2 * line + (sl >> 2);
    int colb = (sl & 3) * 16;
    gB[j] = (const char*)B + (size_t)(bn + row) * K2 + kkj * 64 + colb;
  }
  const int ldst = w * 1024;

#define ISSUE_A(t, kk)                                                        \
  {                                                                           \
    char* Lb = lds[(t) & 1] + (kk) * 16384;                                   \
    gl2lds16(gA[0] + (size_t)(t) * 128 + (kk) * 64, Lb + ldst);               \
    gl2lds16(gA[1] + (size_t)(t) * 128 + (kk) * 64, Lb + 8192 + ldst);        \
  }
#define ISSUE_B(t)                                                            \
  {                                                                           \
    char* Lb = lds[(t) & 1] + 32768;                                          \
    _Pragma("unroll")                                                         \
    for (int j = 0; j < NLB; ++j)                                             \
      gl2lds16(gB[j] + (size_t)(t) * 128, Lb + j * 8192 + ldst);              \
  }

  int offA[4], offB[2][NW];
#pragma unroll
  for (int mi = 0; mi < 4; ++mi) {
    int r = wm * 64 + mi * 16 + l15;
    int line = r >> 1;
    int sl = (((r & 1) << 2) + g) ^ (line & 7);
    offA[mi] = line * 128 + sl * 16;
  }
#pragma unroll
  for (int kk = 0; kk < 2; ++kk)
#pragma unroll
    for (int ni = 0; ni < NW; ++ni) {
      int r = wn * (16 * NW) + ni * 16 + l15;
      int line = r >> 1;
      int sl = (((r & 1) << 2) + g) ^ (line & 7);
      offB[kk][ni] = 32768 + kk * BSUB + line * 128 + sl * 16;
    }

  ISSUE_A(0, 0);
  ISSUE_B(0);
  ISSUE_A(0, 1);
  asm volatile("s_waitcnt vmcnt(2)" ::: "memory");
  FULL_BAR();

  for (int kt = 0; kt < NTt; ++kt) {
    const char* buf = lds[kt & 1];
    const bool pf = (kt + 1) < NTt;
    bf16x8 a[4], b[NW];
#pragma unroll
    for (int mi = 0; mi < 4; ++mi) a[mi] = *(const bf16x8*)(buf + offA[mi]);
#pragma unroll
    for (int ni = 0; ni < NW; ++ni) b[ni] = *(const bf16x8*)(buf + offB[0][ni]);
    if (pf) {
      ISSUE_A(kt + 1, 0);
      ISSUE_B(kt + 1);
      asm volatile("s_waitcnt vmcnt(%0)" ::"i"(2 + NLB) : "memory");
    } else {
      asm volatile("s_waitcnt vmcnt(0)" ::: "memory");
    }
    FULL_BAR();
    __builtin_amdgcn_s_setprio(1);
#pragma unroll
    for (int mi = 0; mi < 4; ++mi)
#pragma unroll
      for (int ni = 0; ni < NW; ++ni)
        acc[mi][ni] = __builtin_amdgcn_mfma_f32_16x16x32_bf16(a[mi], b[ni], acc[mi][ni], 0, 0, 0);
    __builtin_amdgcn_s_setprio(0);
#pragma unroll
    for (int mi = 0; mi < 4; ++mi) a[mi] = *(const bf16x8*)(buf + 16384 + offA[mi]);
#pragma unroll
    for (int ni = 0; ni < NW; ++ni) b[ni] = *(const bf16x8*)(buf + offB[1][ni]);
    if (pf) {
      ISSUE_A(kt + 1, 1);
      asm volatile("s_waitcnt vmcnt(2)" ::: "memory");
    }
    FULL_BAR();
    __builtin_amdgcn_s_setprio(1);
#pragma unroll
    for (int mi = 0; mi < 4; ++mi)
#pragma unroll
      for (int ni = 0; ni < NW; ++ni)
        acc[mi][ni] = __builtin_amdgcn_mfma_f32_16x16x32_bf16(a[mi], b[ni], acc[mi][ni], 0, 0, 0);
    __builtin_amdgcn_s_setprio(0);
  }
#undef ISSUE_A
#undef ISSUE_B

#pragma unroll
  for (int ni = 0; ni < NW; ++ni) {
    int n = bn + wn * (16 * NW) + ni * 16 + l15;
    float bv = bias[n];
    if (EPI == 0) {
#pragma unroll
      for (int mi = 0; mi < 4; ++mi) {
        int m0 = bm + wm * 64 + mi * 16 + 4 * g;
#pragma unroll
        for (int rr = 0; rr < 4; ++rr)
          outb[(size_t)(m0 + rr) * N + n] = f2bf(acc[mi][ni][rr] + bv);
      }
    } else {
#pragma unroll
      for (int mi = 0; mi < 4; ++mi) {
        int m0 = bm + wm * 64 + mi * 16 + 4 * g;
#pragma unroll
        for (int rr = 0; rr < 4; ++rr) outf[(size_t)(m0 + rr) * N + n] = acc[mi][ni][rr] + bv;
      }
    }
  }
}

// ------- flash attention with FUSED 2D-RoPE (q in regs, k at staging) -----
// Constant-work pairs: block b does q-blocks (b, 31-b) = 66 tiles exactly.
// Q-rope: lane-local frag pairs (d0 0,1) half0 / (2,3) half1, 1/sqrt(128)
// folded in. K-rope: staging threads load 8-elem chunks (e0, e0+32) that
// rotate together; o1 = x1*c - x2*s, o2 = x2*c + x1*s.
__global__ __launch_bounds__(256) void attn_kernel(const u16* __restrict__ mixed,
                                                   const int* __restrict__ pid,
                                                   const float* __restrict__ cos_t,
                                                   const float* __restrict__ sin_t,
                                                   u16* __restrict__ ctx) {
  __shared__ __align__(16) u16 Ksh[32 * 136];
  __shared__ __align__(16) u16 Vsh[128 * 32];
  __shared__ __align__(16) u16 Pt[4][16 * 40];

  int tid = threadIdx.x;
  int lane = tid & 63, w = tid >> 6;
  int lane15 = lane & 15, g = lane >> 4;

  int bpair = blockIdx.x & 15;
  int h = blockIdx.x >> 4;

  const u16* qp = mixed + (size_t)h * 384;
  const u16* kp = mixed + (size_t)h * 384 + 128;
  const u16* vp = mixed + (size_t)h * 384 + 256;

  // K staging map: row krow, chunk pair (e0, e0+32)
  int krow = tid >> 3;
  int kc8 = tid & 7;
  int ke0 = (kc8 & 3) * 8 + (kc8 >> 2) * 64;  // 0,8,16,24,64,72,80,88
  int khalf = (kc8 >> 2);                     // 0: cols<64, 1: cols>=64
  int ki0 = ke0 & 31;
  int a_ = tid & 15, b_ = tid >> 4;  // V staging map
  f32x4 z4 = {0.f, 0.f, 0.f, 0.f};
  const float QSC = 0.08838834764831845f;

  for (int pass = 0; pass < 2; ++pass) {
    int qi = pass ? (31 - bpair) : bpair;
    int qbase = qi * 64;
    int qrow = qbase + w * 16 + lane15;
    int ntiles = 2 * qi + 2;

    // ---- load q frags + lane-local rope
    bf16x8 qf[4];
    const u16* qptr = qp + (size_t)qrow * RS + g * 8;
#pragma unroll
    for (int d0 = 0; d0 < 4; ++d0) qf[d0] = *(const bf16x8*)(qptr + d0 * 32);
    {
      int p1 = pid[qrow], p2 = pid[S_LEN + qrow];
      float4 c1a = *(const float4*)(cos_t + p1 * 32 + g * 8);
      float4 c1b = *(const float4*)(cos_t + p1 * 32 + g * 8 + 4);
      float4 s1a = *(const float4*)(sin_t + p1 * 32 + g * 8);
      float4 s1b = *(const float4*)(sin_t + p1 * 32 + g * 8 + 4);
      float4 c2a = *(const float4*)(cos_t + p2 * 32 + g * 8);
      float4 c2b = *(const float4*)(cos_t + p2 * 32 + g * 8 + 4);
      float4 s2a = *(const float4*)(sin_t + p2 * 32 + g * 8);
      float4 s2b = *(const float4*)(sin_t + p2 * 32 + g * 8 + 4);
      float cc[8], ss[8], dd[8], tt[8];
#pragma unroll
      for (int j = 0; j < 4; ++j) {
        cc[j] = ((const float*)&c1a)[j]; cc[4 + j] = ((const float*)&c1b)[j];
        ss[j] = ((const float*)&s1a)[j]; ss[4 + j] = ((const float*)&s1b)[j];
        dd[j] = ((const float*)&c2a)[j]; dd[4 + j] = ((const float*)&c2b)[j];
        tt[j] = ((const float*)&s2a)[j]; tt[4 + j] = ((const float*)&s2b)[j];
      }
#pragma unroll
      for (int j = 0; j < 8; ++j) {
        float x1 = bf2f((u16)qf[0][j]), x2 = bf2f((u16)qf[1][j]);
        qf[0][j] = (short)f2bf((x1 * cc[j] - x2 * ss[j]) * QSC);
        qf[1][j] = (short)f2bf((x2 * cc[j] + x1 * ss[j]) * QSC);
        float y1 = bf2f((u16)qf[2][j]), y2 = bf2f((u16)qf[3][j]);
        qf[2][j] = (short)f2bf((y1 * dd[j] - y2 * tt[j]) * QSC);
        qf[3][j] = (short)f2bf((y2 * dd[j] + y1 * tt[j]) * QSC);
      }
    }

    f32x4 pv[8];
#pragma unroll
    for (int db = 0; db < 8; ++db) pv[db] = z4;
    float m_run = -1e30f, l_run = 0.0f;

    for (int t = 0; t < ntiles; ++t) {
      int kb0 = t * 32;
      __syncthreads();
      {
        // ---- K staging with fused rope
        int p = pid[khalf * S_LEN + kb0 + krow];
        const u16* rowp = kp + (size_t)(kb0 + krow) * RS;
        bf16x8 x1 = *(const bf16x8*)(rowp + ke0);
        bf16x8 x2 = *(const bf16x8*)(rowp + ke0 + 32);
        float4 ca = *(const float4*)(cos_t + p * 32 + ki0);
        float4 cb = *(const float4*)(cos_t + p * 32 + ki0 + 4);
        float4 sa = *(const float4*)(sin_t + p * 32 + ki0);
        float4 sb = *(const float4*)(sin_t + p * 32 + ki0 + 4);
        bf16x8 o1, o2;
#pragma unroll
        for (int j = 0; j < 8; ++j) {
          float c = (j < 4) ? ((const float*)&ca)[j] : ((const float*)&cb)[j - 4];
          float s = (j < 4) ? ((const float*)&sa)[j] : ((const float*)&sb)[j - 4];
          float v1 = bf2f((u16)x1[j]), v2 = bf2f((u16)x2[j]);
          o1[j] = (short)f2bf(v1 * c - v2 * s);
          o2[j] = (short)f2bf(v2 * c + v1 * s);
        }
        *(bf16x8*)(Ksh + krow * 136 + ke0) = o1;
        *(bf16x8*)(Ksh + krow * 136 + ke0 + 32) = o2;
        // ---- V staging (no rope), packed b32, block-swizzled transpose
        int k0 = 2 * a_, d0 = 8 * b_;
        bf16x8 r0 = *(const bf16x8*)(vp + (size_t)(kb0 + k0) * RS + d0);
        bf16x8 r1 = *(const bf16x8*)(vp + (size_t)(kb0 + k0 + 1) * RS + d0);
#pragma unroll
        for (int jj = 0; jj < 8; ++jj) {
          int d = d0 + jj;
          u32 val = (u32)(u16)r0[jj] | ((u32)(u16)r1[jj] << 16);
          *(u32*)(Vsh + d * 32 + (((k0 >> 3) ^ (d & 3)) << 3) + (k0 & 7)) = val;
        }
      }
      __syncthreads();

      f32x4 sa0 = z4, sa1 = z4;
#pragma unroll
      for (int d0 = 0; d0 < 4; ++d0) {
        bf16x8 k0f = *(const bf16x8*)(Ksh + lane15 * 136 + d0 * 32 + g * 8);
        bf16x8 k1f = *(const bf16x8*)(Ksh + (16 + lane15) * 136 + d0 * 32 + g * 8);
        sa0 = __builtin_amdgcn_mfma_f32_16x16x32_bf16(k0f, qf[d0], sa0, 0, 0, 0);
        sa1 = __builtin_amdgcn_mfma_f32_16x16x32_bf16(k1f, qf[d0], sa1, 0, 0, 0);
      }
      float s[8];
#pragma unroll
      for (int rr = 0; rr < 4; ++rr) {
        int kg0 = kb0 + 4 * g + rr;
        int kg1 = kb0 + 16 + 4 * g + rr;
        s[rr] = (kg0 > qrow) ? -1e30f : sa0[rr];
        s[4 + rr] = (kg1 > qrow) ? -1e30f : sa1[rr];
      }
      float mx = s[0];
#pragma unroll
      for (int i2 = 1; i2 < 8; ++i2) mx = fmaxf(mx, s[i2]);
      mx = fmaxf(mx, __shfl_xor(mx, 16));
      mx = fmaxf(mx, __shfl_xor(mx, 32));
      float mnew = fmaxf(m_run, mx);
      float fac = exp2f((m_run - mnew) * 1.4426950408889634f);
      float p[8], psum = 0.f;
#pragma unroll
      for (int i2 = 0; i2 < 8; ++i2) {
        p[i2] = exp2f((s[i2] - mnew) * 1.4426950408889634f);
        psum += p[i2];
      }
      psum += __shfl_xor(psum, 16);
      psum += __shfl_xor(psum, 32);
      l_run = l_run * fac + psum;
      m_run = mnew;
#pragma unroll
      for (int db = 0; db < 8; ++db) pv[db] *= fac;

      u32 w0 = (u32)f2bf(p[0]) | ((u32)f2bf(p[1]) << 16);
      u32 w1 = (u32)f2bf(p[2]) | ((u32)f2bf(p[3]) << 16);
      u32 w2 = (u32)f2bf(p[4]) | ((u32)f2bf(p[5]) << 16);
      u32 w3 = (u32)f2bf(p[6]) | ((u32)f2bf(p[7]) << 16);
      u32x2 pa, pb;
      pa.x = w0; pa.y = w1; pb.x = w2; pb.y = w3;
      *(u32x2*)(&Pt[w][lane15 * 40 + 4 * g]) = pa;
      *(u32x2*)(&Pt[w][lane15 * 40 + 16 + 4 * g]) = pb;
      asm volatile("s_waitcnt lgkmcnt(0)" ::: "memory");
      bf16x8 pfrag = *(const bf16x8*)(&Pt[w][lane15 * 40 + 8 * g]);

#pragma unroll
      for (int db = 0; db < 8; ++db) {
        int d = db * 16 + lane15;
        bf16x8 vf = *(const bf16x8*)(Vsh + d * 32 + ((g ^ (d & 3)) << 3));
        pv[db] = __builtin_amdgcn_mfma_f32_16x16x32_bf16(vf, pfrag, pv[db], 0, 0, 0);
      }
    }

    float inv = 1.0f / l_run;
#pragma unroll
    for (int db = 0; db < 8; ++db) {
      ushort4 o;
      o.x = f2bf(pv[db][0] * inv);
      o.y = f2bf(pv[db][1] * inv);
      o.z = f2bf(pv[db][2] * inv);
      o.w = f2bf(pv[db][3] * inv);
      *(ushort4*)(ctx + (size_t)qrow * HID + h * HDD + db * 16 + 4 * g) = o;
    }
    __syncthreads();  // LDS reuse safety across passes
  }
}

// ---------------- launcher -------------------------------------------------
extern "C" void kernel_launch(void* const* d_in, const int* in_sizes, int n_in,
                              void* d_out, int out_size, void* d_ws, size_t ws_size,
                              hipStream_t stream) {
  const float* hidden = (const float*)d_in[0];
  const int* pid = (const int*)d_in[1];
  const float* wqkv = (const float*)d_in[3];
  const float* bqkv = (const float*)d_in[4];
  const float* wdense = (const float*)d_in[5];
  const float* bdense = (const float*)d_in[6];
  float* out = (float*)d_out;

  char* ws = (char*)d_ws;
  u16* W1 = (u16*)ws;                        // [12288][4096] bf16
  u16* W2 = (u16*)(ws + 100663296);          // [4096][4096] bf16
  u16* X = (u16*)(ws + 134217728);           // [2048][4096] bf16
  u16* mixed = (u16*)(ws + 150994944);       // [2048][12288] bf16
  u16* ctx = (u16*)(ws + 201326592);         // [2048][4096] bf16
  float* cos_t = (float*)(ws + 218103808);
  float* sin_t = (float*)(ws + 218365952);

  cvt3_kernel<<<dim3(2048), dim3(256), 0, stream>>>(
      wqkv, W1, N_QKV * KDIM / 4, wdense, W2, HID * KDIM / 4, hidden, X, S_LEN * HID / 4,
      cos_t, sin_t);

  // QKV: 256x384 tile -> 8 M x 32 N = 256 blocks = 1.00 exact round
  gemmQ<<<dim3(256), dim3(512), 0, stream>>>(X, W1, bqkv, mixed);

  // attention with fused rope (rope kernel eliminated)
  attn_kernel<<<dim3(512), dim3(256), 0, stream>>>(mixed, pid, cos_t, sin_t, ctx);

  // dense: BN=128 -> 8 M x 32 N = 256 blocks = 1.00 exact round
  gemmK<4, 1><<<dim3(256), dim3(512), 0, stream>>>(
      ctx, W2, bdense, HID, 64, nullptr, out);
}

// Round 11
// 492.919 us; speedup vs baseline: 1.0154x; 1.0089x over previous
//
#include <hip/hip_runtime.h>

typedef unsigned short u16;
typedef unsigned int u32;
typedef __attribute__((ext_vector_type(4))) float f32x4;
typedef __attribute__((ext_vector_type(8))) short bf16x8;
typedef __attribute__((ext_vector_type(2))) unsigned int u32x2;

#define S_LEN 2048
#define NHEAD 32
#define HDD 128
#define HID 4096
#define N_QKV 12288
#define KDIM 4096
#define RS 12288  // mixed row stride (elements)

__device__ __forceinline__ u16 f2bf(float f) {
  u32 u = __builtin_bit_cast(u32, f);
  u = (u + 0x7FFFu + ((u >> 16) & 1u)) >> 16;
  return (u16)u;
}
__device__ __forceinline__ float bf2f(u16 h) {
  u32 u = ((u32)h) << 16;
  return __builtin_bit_cast(float, u);
}

__device__ __forceinline__ void gl2lds16(const void* g, void* l) {
  __builtin_amdgcn_global_load_lds(
      (const __attribute__((address_space(1))) u32*)g,
      (__attribute__((address_space(3))) u32*)l, 16, 0, 0);
}

#define FULL_BAR()                          \
  {                                         \
    asm volatile("" ::: "memory");          \
    __builtin_amdgcn_s_barrier();           \
    asm volatile("" ::: "memory");          \
  }

// ------ fused fp32 -> bf16 conversion (W1, X) + RoPE trig tables ----------
// W2 is no longer converted here — the dense GEMM reads it as fp32 directly.
__global__ __launch_bounds__(256) void cvt3_kernel(const float* __restrict__ s0, u16* __restrict__ d0, int n0,
                                                   const float* __restrict__ s2, u16* __restrict__ d2, int n2,
                                                   float* __restrict__ cos_t, float* __restrict__ sin_t) {
  int i = blockIdx.x * blockDim.x + threadIdx.x;
  if (i < S_LEN * 32) {
    int s = i >> 5, ii = i & 31;
    float invf = expf(-0.28782313662425572f * (float)ii);
    float a = (float)s * invf;
    cos_t[i] = cosf(a);
    sin_t[i] = sinf(a);
  }
  int st = gridDim.x * blockDim.x;
  int ntot = n0 + n2;
  for (; i < ntot; i += st) {
    const float* s;
    u16* d;
    int j = i;
    if (j < n0) {
      s = s0; d = d0;
    } else {
      j -= n0; s = s2; d = d2;
    }
    float4 v = ((const float4*)s)[j];
    u32x2 o;
    o.x = (u32)f2bf(v.x) | ((u32)f2bf(v.y) << 16);
    o.y = (u32)f2bf(v.z) | ((u32)f2bf(v.w) << 16);
    ((u32x2*)d)[j] = o;
  }
}

// ---------------- standalone K-rope (K columns of mixed only) -------------
__global__ __launch_bounds__(256) void ropek_kernel(u16* __restrict__ mixed,
                                                    const int* __restrict__ pid,
                                                    const float* __restrict__ cos_t,
                                                    const float* __restrict__ sin_t) {
  int idx = blockIdx.x * blockDim.x + threadIdx.x;
  const int total = NHEAD * S_LEN * 2 * 8;  // 2^20
  if (idx >= total) return;
  int j = idx & 7;
  int half = (idx >> 3) & 1;
  int s = (idx >> 4) & (S_LEN - 1);
  int h = idx >> 15;
  int i0 = j * 4;
  int p = pid[half * S_LEN + s];
  float4 c4 = *(const float4*)(cos_t + p * 32 + i0);
  float4 s4 = *(const float4*)(sin_t + p * 32 + i0);
  u16* base = mixed + (size_t)s * RS + h * 384 + 128 + half * 64 + i0;
  ushort4 x1v = *(const ushort4*)(base);
  ushort4 x2v = *(const ushort4*)(base + 32);
  ushort4 o1, o2;
  {
    float x1 = bf2f(x1v.x), x2 = bf2f(x2v.x);
    o1.x = f2bf(x1 * c4.x - x2 * s4.x);
    o2.x = f2bf(x2 * c4.x + x1 * s4.x);
  }
  {
    float x1 = bf2f(x1v.y), x2 = bf2f(x2v.y);
    o1.y = f2bf(x1 * c4.y - x2 * s4.y);
    o2.y = f2bf(x2 * c4.y + x1 * s4.y);
  }
  {
    float x1 = bf2f(x1v.z), x2 = bf2f(x2v.z);
    o1.z = f2bf(x1 * c4.z - x2 * s4.z);
    o2.z = f2bf(x2 * c4.z + x1 * s4.z);
  }
  {
    float x1 = bf2f(x1v.w), x2 = bf2f(x2v.w);
    o1.w = f2bf(x1 * c4.w - x2 * s4.w);
    o2.w = f2bf(x2 * c4.w + x1 * s4.w);
  }
  *(ushort4*)(base) = o1;
  *(ushort4*)(base + 32) = o2;
}

// -------- QKV GEMM: 256x384 tile, BK=32, ring-3 LDS (unchanged, 210us) ----
__global__ __launch_bounds__(512, 2) void gemmQ(const u16* __restrict__ A,
                                                const u16* __restrict__ B,
                                                const float* __restrict__ bias,
                                                u16* __restrict__ outb) {
  __shared__ __align__(16) char lds[3][40960];

  const int tid = threadIdx.x;
  const int lane = tid & 63, w = tid >> 6;
  const int l15 = lane & 15, g = lane >> 4;
  const int wm = w >> 2, wn = w & 3;

  int x = blockIdx.x & 7, loc = blockIdx.x >> 3;
  int mb = loc & 7, nb = x * 4 + (loc >> 3);
  const int bm = mb * 256, bn = nb * 384;

  f32x4 acc[8][6];
  f32x4 z4 = {0.f, 0.f, 0.f, 0.f};
#pragma unroll
  for (int mi = 0; mi < 8; ++mi)
#pragma unroll
    for (int ni = 0; ni < 6; ++ni) acc[mi][ni] = z4;

  const size_t K2 = (size_t)KDIM * 2;

  const char* gA[2];
#pragma unroll
  for (int j = 0; j < 2; ++j) {
    int slot = j * 512 + tid;
    int line = slot >> 3;
    int sl = (slot & 7) ^ (line & 7);
    int row = 2 * line + (sl >> 2);
    int colb = (sl & 3) * 16;
    gA[j] = (const char*)A + (size_t)(bm + row) * K2 + colb;
  }
  const char* gB[3];
#pragma unroll
  for (int j = 0; j < 3; ++j) {
    int slot = j * 512 + tid;
    int line = slot >> 3;
    int sl = (slot & 7) ^ (line & 7);
    int row = 2 * line + (sl >> 2);
    int colb = (sl & 3) * 16;
    gB[j] = (const char*)B + (size_t)(bn + row) * K2 + colb;
  }
  const int ldst = w * 1024;

#define QIA(t, bi)                                                  \
  {                                                                 \
    char* Lb = lds[bi];                                             \
    gl2lds16(gA[0] + (size_t)(t) * 64, Lb + ldst);                  \
    gl2lds16(gA[1] + (size_t)(t) * 64, Lb + 8192 + ldst);           \
  }
#define QIB(t, bi)                                                  \
  {                                                                 \
    char* Lb = lds[bi] + 16384;                                     \
    _Pragma("unroll")                                               \
    for (int j = 0; j < 3; ++j)                                     \
      gl2lds16(gB[j] + (size_t)(t) * 64, Lb + j * 8192 + ldst);     \
  }

  int offA[8], offB[6];
#pragma unroll
  for (int mi = 0; mi < 8; ++mi) {
    int r = wm * 128 + mi * 16 + l15;
    int line = r >> 1;
    int sl = (((r & 1) << 2) + g) ^ (line & 7);
    offA[mi] = line * 128 + sl * 16;
  }
#pragma unroll
  for (int ni = 0; ni < 6; ++ni) {
    int r = wn * 96 + ni * 16 + l15;
    int line = r >> 1;
    int sl = (((r & 1) << 2) + g) ^ (line & 7);
    offB[ni] = 16384 + line * 128 + sl * 16;
  }

  QIA(0, 0); QIB(0, 0);
  QIA(1, 1); QIB(1, 1);
  asm volatile("s_waitcnt vmcnt(5)" ::: "memory");
  FULL_BAR();

  int cur = 0, nx2 = 2;
  for (int kt = 0; kt < 128; ++kt) {
    const char* buf = lds[cur];
    const bool pf = (kt + 2) < 128;
    bf16x8 a[4], b[6];
#pragma unroll
    for (int mi = 0; mi < 4; ++mi) a[mi] = *(const bf16x8*)(buf + offA[mi]);
#pragma unroll
    for (int ni = 0; ni < 6; ++ni) b[ni] = *(const bf16x8*)(buf + offB[ni]);
    if (pf) QIA(kt + 2, nx2);
    FULL_BAR();
    __builtin_amdgcn_s_setprio(1);
#pragma unroll
    for (int mi = 0; mi < 4; ++mi)
#pragma unroll
      for (int ni = 0; ni < 6; ++ni)
        acc[mi][ni] = __builtin_amdgcn_mfma_f32_16x16x32_bf16(a[mi], b[ni], acc[mi][ni], 0, 0, 0);
    __builtin_amdgcn_s_setprio(0);
#pragma unroll
    for (int mi = 0; mi < 4; ++mi) a[mi] = *(const bf16x8*)(buf + offA[4 + mi]);
    if (pf) {
      QIB(kt + 2, nx2);
      asm volatile("s_waitcnt vmcnt(5)" ::: "memory");
    } else if (kt == 126) {
      asm volatile("s_waitcnt vmcnt(0)" ::: "memory");
    }
    FULL_BAR();
    __builtin_amdgcn_s_setprio(1);
#pragma unroll
    for (int mi = 0; mi < 4; ++mi)
#pragma unroll
      for (int ni = 0; ni < 6; ++ni)
        acc[4 + mi][ni] = __builtin_amdgcn_mfma_f32_16x16x32_bf16(a[mi], b[ni], acc[4 + mi][ni], 0, 0, 0);
    __builtin_amdgcn_s_setprio(0);
    cur = (cur + 1 == 3) ? 0 : cur + 1;
    nx2 = (nx2 + 1 == 3) ? 0 : nx2 + 1;
  }
#undef QIA
#undef QIB

#pragma unroll
  for (int ni = 0; ni < 6; ++ni) {
    int n = bn + wn * 96 + ni * 16 + l15;
    float bv = bias[n];
#pragma unroll
    for (int mi = 0; mi < 8; ++mi) {
      int m0 = bm + wm * 128 + mi * 16 + 4 * g;
#pragma unroll
      for (int rr = 0; rr < 4; ++rr)
        outb[(size_t)(m0 + rr) * N_QKV + n] = f2bf(acc[mi][ni][rr] + bv);
    }
  }
}

// -------- dense GEMM: 256x128, BK=64, A(bf16) gload_lds + B(fp32) reg-cvt --
// C = ctx * W2^T + bias -> f32 out.  W2 read DIRECTLY as fp32 (no cvt pass);
// staged global->reg, f2bf convert (identical rounding to cvt path), then
// ds_write into the swizzled bf16 layout.
// 512 thr = 8 waves (4M x 2N), per-wave 64x64, acc[4][4].
// LDS buf = A: 2x16KB (kk units) | B: 2x8KB (kk subunits) = 48KB; ring-2.
// Ledger (queue never <2): entering ph0(t): A(t,1)x2 outstanding.
//  ph0: frags kk0 | ISSUE_A(t+1,0)x2 + GLOADB(t+1)x4 -> vmcnt(6) certifies
//       A(t,1) | BAR | 16 MFMA
//  ph1: frags kk1 | ISSUE_A(t+1,1)x2 -> vmcnt(2) certifies A(t+1,0)+B-regs
//       | cvt+ds_write B(t+1) | lgkmcnt(0) | BAR | 16 MFMA
__global__ __launch_bounds__(512, 2) void gemmD(const u16* __restrict__ A,
                                                const float* __restrict__ Bf,
                                                const float* __restrict__ bias,
                                                float* __restrict__ outf) {
  __shared__ __align__(16) char lds[2][49152];

  const int tid = threadIdx.x;
  const int lane = tid & 63, w = tid >> 6;
  const int l15 = lane & 15, g = lane >> 4;
  const int wm = w >> 1, wn = w & 1;  // 4M x 2N

  // 256 blocks: perx=32, npx=4, M-fastest
  int x = blockIdx.x & 7, loc = blockIdx.x >> 3;
  int mb = loc & 7, nb = x * 4 + (loc >> 3);
  const int bm = mb * 256, bn = nb * 128;

  f32x4 acc[4][4];
  f32x4 z4 = {0.f, 0.f, 0.f, 0.f};
#pragma unroll
  for (int mi = 0; mi < 4; ++mi)
#pragma unroll
    for (int ni = 0; ni < 4; ++ni) acc[mi][ni] = z4;

  const size_t K2 = (size_t)KDIM * 2;

  // A staging (per kk unit: 256 rows x 64B, paired-row swizzle, 2 glds)
  const char* gA[2];
#pragma unroll
  for (int j = 0; j < 2; ++j) {
    int slot = j * 512 + tid;
    int line = slot >> 3;
    int sl = (slot & 7) ^ (line & 7);
    int row = 2 * line + (sl >> 2);
    int colb = (sl & 3) * 16;
    gA[j] = (const char*)A + (size_t)(bm + row) * K2 + colb;
  }
  // B reg-staging: thread covers logical slot tid in BOTH kk subunits.
  int bline = tid >> 3;
  int bsl = tid & 7;
  int brow = 2 * bline + (bsl >> 2);
  int bcole = (bsl & 3) * 8;
  const float* gBs = Bf + (size_t)(bn + brow) * KDIM + bcole;
  int bphys = bsl ^ (bline & 7);
  const int bwr = 32768 + bline * 128 + bphys * 16;  // + kk*8192
  const int ldst = w * 1024;

#define DIA(t, kk)                                                            \
  {                                                                           \
    char* Lb = lds[(t) & 1] + (kk) * 16384;                                   \
    gl2lds16(gA[0] + (size_t)(t) * 128 + (kk) * 64, Lb + ldst);               \
    gl2lds16(gA[1] + (size_t)(t) * 128 + (kk) * 64, Lb + 8192 + ldst);        \
  }
#define DGB(t)                                                                \
  {                                                                           \
    const float* p0 = gBs + (size_t)(t) * 64;                                 \
    b0a = *(const float4*)(p0);                                               \
    b0b = *(const float4*)(p0 + 4);                                           \
    b1a = *(const float4*)(p0 + 32);                                          \
    b1b = *(const float4*)(p0 + 36);                                          \
  }
#define DWB(t)                                                                \
  {                                                                           \
    bf16x8 o0, o1;                                                            \
    o0[0] = (short)f2bf(b0a.x); o0[1] = (short)f2bf(b0a.y);                   \
    o0[2] = (short)f2bf(b0a.z); o0[3] = (short)f2bf(b0a.w);                   \
    o0[4] = (short)f2bf(b0b.x); o0[5] = (short)f2bf(b0b.y);                   \
    o0[6] = (short)f2bf(b0b.z); o0[7] = (short)f2bf(b0b.w);                   \
    o1[0] = (short)f2bf(b1a.x); o1[1] = (short)f2bf(b1a.y);                   \
    o1[2] = (short)f2bf(b1a.z); o1[3] = (short)f2bf(b1a.w);                   \
    o1[4] = (short)f2bf(b1b.x); o1[5] = (short)f2bf(b1b.y);                   \
    o1[6] = (short)f2bf(b1b.z); o1[7] = (short)f2bf(b1b.w);                   \
    char* Lb = lds[(t) & 1];                                                  \
    *(bf16x8*)(Lb + bwr) = o0;                                                \
    *(bf16x8*)(Lb + 8192 + bwr) = o1;                                         \
  }

  // fragment offsets (paired-row swizzle)
  int offA[4], offB[2][4];
#pragma unroll
  for (int mi = 0; mi < 4; ++mi) {
    int r = wm * 64 + mi * 16 + l15;
    int line = r >> 1;
    int sl = (((r & 1) << 2) + g) ^ (line & 7);
    offA[mi] = line * 128 + sl * 16;
  }
#pragma unroll
  for (int kk = 0; kk < 2; ++kk)
#pragma unroll
    for (int ni = 0; ni < 4; ++ni) {
      int r = wn * 64 + ni * 16 + l15;
      int line = r >> 1;
      int sl = (((r & 1) << 2) + g) ^ (line & 7);
      offB[kk][ni] = 32768 + kk * 8192 + line * 128 + sl * 16;
    }

  float4 b0a, b0b, b1a, b1b;
  // prologue: B(0)->regs, A(0) issued; certify B regs; write B(0); drain all
  DGB(0);
  DIA(0, 0);
  DIA(0, 1);
  asm volatile("s_waitcnt vmcnt(4)" ::: "memory");
  DWB(0);
  asm volatile("s_waitcnt vmcnt(0) lgkmcnt(0)" ::: "memory");
  FULL_BAR();

  for (int kt = 0; kt < 64; ++kt) {
    const char* buf = lds[kt & 1];
    const bool pf = (kt + 1) < 64;
    bf16x8 a[4], b[4];
    // ph0: kk0
#pragma unroll
    for (int mi = 0; mi < 4; ++mi) a[mi] = *(const bf16x8*)(buf + offA[mi]);
#pragma unroll
    for (int ni = 0; ni < 4; ++ni) b[ni] = *(const bf16x8*)(buf + offB[0][ni]);
    if (pf) {
      DIA(kt + 1, 0);
      DGB(kt + 1);
      asm volatile("s_waitcnt vmcnt(6)" ::: "memory");
    } else {
      asm volatile("s_waitcnt vmcnt(0)" ::: "memory");
    }
    FULL_BAR();
    __builtin_amdgcn_s_setprio(1);
#pragma unroll
    for (int mi = 0; mi < 4; ++mi)
#pragma unroll
      for (int ni = 0; ni < 4; ++ni)
        acc[mi][ni] = __builtin_amdgcn_mfma_f32_16x16x32_bf16(a[mi], b[ni], acc[mi][ni], 0, 0, 0);
    __builtin_amdgcn_s_setprio(0);
    // ph1: kk1
#pragma unroll
    for (int mi = 0; mi < 4; ++mi) a[mi] = *(const bf16x8*)(buf + 16384 + offA[mi]);
#pragma unroll
    for (int ni = 0; ni < 4; ++ni) b[ni] = *(const bf16x8*)(buf + offB[1][ni]);
    if (pf) {
      DIA(kt + 1, 1);
      asm volatile("s_waitcnt vmcnt(2)" ::: "memory");
      DWB(kt + 1);
      asm volatile("s_waitcnt lgkmcnt(0)" ::: "memory");
    }
    FULL_BAR();
    __builtin_amdgcn_s_setprio(1);
#pragma unroll
    for (int mi = 0; mi < 4; ++mi)
#pragma unroll
      for (int ni = 0; ni < 4; ++ni)
        acc[mi][ni] = __builtin_amdgcn_mfma_f32_16x16x32_bf16(a[mi], b[ni], acc[mi][ni], 0, 0, 0);
    __builtin_amdgcn_s_setprio(0);
  }
#undef DIA
#undef DGB
#undef DWB

  // epilogue: D row(M) = 4*g + reg, col(N) = l15; f32 out + bias
#pragma unroll
  for (int ni = 0; ni < 4; ++ni) {
    int n = bn + wn * 64 + ni * 16 + l15;
    float bv = bias[n];
#pragma unroll
    for (int mi = 0; mi < 4; ++mi) {
      int m0 = bm + wm * 64 + mi * 16 + 4 * g;
#pragma unroll
      for (int rr = 0; rr < 4; ++rr) outf[(size_t)(m0 + rr) * HID + n] = acc[mi][ni][rr] + bv;
    }
  }
}

// ------- flash attention, KVBLK=64, fused Q-rope, constant-work pairs -----
// Block b: q-blocks (b, 31-b) sequentially -> (b+1)+(32-b) = 33 tiles exact.
// KVBLK=64 halves per-K softmax/rescale/barrier overhead vs KVBLK=32.
__global__ __launch_bounds__(256) void attn_kernel(const u16* __restrict__ mixed,
                                                   const int* __restrict__ pid,
                                                   const float* __restrict__ cos_t,
                                                   const float* __restrict__ sin_t,
                                                   u16* __restrict__ ctx) {
  __shared__ __align__(16) u16 Ksh[64 * 136];   // [k][d], pad 136
  __shared__ __align__(16) u16 Vsh[128 * 64];   // [d][k], 16B-slot xor swizzle
  __shared__ __align__(16) u16 Pt[4][16 * 72];  // per-wave P^T [q][k], pad 72

  int tid = threadIdx.x;
  int lane = tid & 63, w = tid >> 6;
  int lane15 = lane & 15, g = lane >> 4;

  int bpair = blockIdx.x & 15;
  int h = blockIdx.x >> 4;

  const u16* qp = mixed + (size_t)h * 384;
  const u16* kp = mixed + (size_t)h * 384 + 128;
  const u16* vp = mixed + (size_t)h * 384 + 256;

  // K staging: row = tid>>2 (0..63), 32-elem chunk (tid&3)*32
  int krow = tid >> 2, kc = (tid & 3) * 32;
  // V staging: k-pair 2*(tid&31), d-chunk (tid>>5)*16
  int vk0 = 2 * (tid & 31), vd0 = (tid >> 5) * 16;
  f32x4 z4 = {0.f, 0.f, 0.f, 0.f};
  const float QSC = 0.08838834764831845f;
  const float L2E = 1.4426950408889634f;

  for (int pass = 0; pass < 2; ++pass) {
    int qi = pass ? (31 - bpair) : bpair;
    int qbase = qi * 64;
    int qrow = qbase + w * 16 + lane15;
    int ntiles = qi + 1;

    // ---- load q frags + lane-local 2D rope (1/sqrt(128) folded)
    bf16x8 qf[4];
    const u16* qptr = qp + (size_t)qrow * RS + g * 8;
#pragma unroll
    for (int d0 = 0; d0 < 4; ++d0) qf[d0] = *(const bf16x8*)(qptr + d0 * 32);
    {
      int p1 = pid[qrow], p2 = pid[S_LEN + qrow];
      float cc[8], ss[8], dd[8], tt[8];
#pragma unroll
      for (int j = 0; j < 8; ++j) {
        cc[j] = cos_t[p1 * 32 + g * 8 + j];
        ss[j] = sin_t[p1 * 32 + g * 8 + j];
        dd[j] = cos_t[p2 * 32 + g * 8 + j];
        tt[j] = sin_t[p2 * 32 + g * 8 + j];
      }
#pragma unroll
      for (int j = 0; j < 8; ++j) {
        float x1 = bf2f((u16)qf[0][j]), x2 = bf2f((u16)qf[1][j]);
        qf[0][j] = (short)f2bf((x1 * cc[j] - x2 * ss[j]) * QSC);
        qf[1][j] = (short)f2bf((x2 * cc[j] + x1 * ss[j]) * QSC);
        float y1 = bf2f((u16)qf[2][j]), y2 = bf2f((u16)qf[3][j]);
        qf[2][j] = (short)f2bf((y1 * dd[j] - y2 * tt[j]) * QSC);
        qf[3][j] = (short)f2bf((y2 * dd[j] + y1 * tt[j]) * QSC);
      }
    }

    f32x4 pv[8];
#pragma unroll
    for (int db = 0; db < 8; ++db) pv[db] = z4;
    float m_run = -1e30f, l_run = 0.0f;

    for (int t = 0; t < ntiles; ++t) {
      int kb0 = t * 64;
      __syncthreads();
      {
        // K: plain copy (already roped by ropek_kernel)
        const bf16x8* src = (const bf16x8*)(kp + (size_t)(kb0 + krow) * RS + kc);
#pragma unroll
        for (int c = 0; c < 4; ++c)
          *(bf16x8*)(Ksh + krow * 136 + kc + c * 8) = src[c];
        // V: transpose into [d][64k] with 8-slot xor swizzle, packed u32
        const bf16x8* r0p = (const bf16x8*)(vp + (size_t)(kb0 + vk0) * RS + vd0);
        const bf16x8* r1p = (const bf16x8*)(vp + (size_t)(kb0 + vk0 + 1) * RS + vd0);
        bf16x8 r00 = r0p[0], r01 = r0p[1];
        bf16x8 r10 = r1p[0], r11 = r1p[1];
#pragma unroll
        for (int jj = 0; jj < 8; ++jj) {
          int d = vd0 + jj;
          u32 v0 = (u32)(u16)r00[jj] | ((u32)(u16)r10[jj] << 16);
          *(u32*)((char*)Vsh + d * 128 + (((vk0 >> 3) ^ (d & 7)) << 4) + (vk0 & 7) * 2) = v0;
          int d2 = vd0 + 8 + jj;
          u32 v1 = (u32)(u16)r01[jj] | ((u32)(u16)r11[jj] << 16);
          *(u32*)((char*)Vsh + d2 * 128 + (((vk0 >> 3) ^ (d2 & 7)) << 4) + (vk0 & 7) * 2) = v1;
        }
      }
      __syncthreads();

      // S^T = K * Q^T: 4 k-row groups of 16
      f32x4 sa[4];
#pragma unroll
      for (int kt16 = 0; kt16 < 4; ++kt16) sa[kt16] = z4;
#pragma unroll
      for (int kt16 = 0; kt16 < 4; ++kt16)
#pragma unroll
        for (int d0 = 0; d0 < 4; ++d0) {
          bf16x8 kf = *(const bf16x8*)(Ksh + (kt16 * 16 + lane15) * 136 + d0 * 32 + g * 8);
          sa[kt16] = __builtin_amdgcn_mfma_f32_16x16x32_bf16(kf, qf[d0], sa[kt16], 0, 0, 0);
        }
      float s[16];
#pragma unroll
      for (int kt16 = 0; kt16 < 4; ++kt16)
#pragma unroll
        for (int rr = 0; rr < 4; ++rr) {
          int kg = kb0 + kt16 * 16 + 4 * g + rr;
          s[kt16 * 4 + rr] = (kg > qrow) ? -1e30f : sa[kt16][rr];
        }
      float mx = s[0];
#pragma unroll
      for (int i2 = 1; i2 < 16; ++i2) mx = fmaxf(mx, s[i2]);
      mx = fmaxf(mx, __shfl_xor(mx, 16));
      mx = fmaxf(mx, __shfl_xor(mx, 32));
      float mnew = fmaxf(m_run, mx);
      float fac = exp2f((m_run - mnew) * L2E);
      float p[16], psum = 0.f;
#pragma unroll
      for (int i2 = 0; i2 < 16; ++i2) {
        p[i2] = exp2f((s[i2] - mnew) * L2E);
        psum += p[i2];
      }
      psum += __shfl_xor(psum, 16);
      psum += __shfl_xor(psum, 32);
      l_run = l_run * fac + psum;
      m_run = mnew;
#pragma unroll
      for (int db = 0; db < 8; ++db) pv[db] *= fac;

      // P^T -> Pt: lane has k = kt16*16 + 4g + r for q-col lane15
#pragma unroll
      for (int kt16 = 0; kt16 < 4; ++kt16) {
        u32x2 pw;
        pw.x = (u32)f2bf(p[kt16 * 4 + 0]) | ((u32)f2bf(p[kt16 * 4 + 1]) << 16);
        pw.y = (u32)f2bf(p[kt16 * 4 + 2]) | ((u32)f2bf(p[kt16 * 4 + 3]) << 16);
        *(u32x2*)(&Pt[w][lane15 * 72 + kt16 * 16 + 4 * g]) = pw;
      }
      asm volatile("s_waitcnt lgkmcnt(0)" ::: "memory");
      bf16x8 pf0 = *(const bf16x8*)(&Pt[w][lane15 * 72 + 8 * g]);
      bf16x8 pf1 = *(const bf16x8*)(&Pt[w][lane15 * 72 + 32 + 8 * g]);

      // PV: C^T[d][q] += V^T[d][k] * P^T[k][q], k split 0-31 / 32-63
#pragma unroll
      for (int db = 0; db < 8; ++db) {
        int d = db * 16 + lane15;
        bf16x8 vf0 = *(const bf16x8*)((const char*)Vsh + d * 128 + ((g ^ (d & 7)) << 4));
        bf16x8 vf1 = *(const bf16x8*)((const char*)Vsh + d * 128 + (((4 + g) ^ (d & 7)) << 4));
        pv[db] = __builtin_amdgcn_mfma_f32_16x16x32_bf16(vf0, pf0, pv[db], 0, 0, 0);
        pv[db] = __builtin_amdgcn_mfma_f32_16x16x32_bf16(vf1, pf1, pv[db], 0, 0, 0);
      }
    }

    float inv = 1.0f / l_run;
#pragma unroll
    for (int db = 0; db < 8; ++db) {
      ushort4 o;
      o.x = f2bf(pv[db][0] * inv);
      o.y = f2bf(pv[db][1] * inv);
      o.z = f2bf(pv[db][2] * inv);
      o.w = f2bf(pv[db][3] * inv);
      *(ushort4*)(ctx + (size_t)qrow * HID + h * HDD + db * 16 + 4 * g) = o;
    }
    __syncthreads();
  }
}

// ---------------- launcher -------------------------------------------------
extern "C" void kernel_launch(void* const* d_in, const int* in_sizes, int n_in,
                              void* d_out, int out_size, void* d_ws, size_t ws_size,
                              hipStream_t stream) {
  const float* hidden = (const float*)d_in[0];
  const int* pid = (const int*)d_in[1];
  const float* wqkv = (const float*)d_in[3];
  const float* bqkv = (const float*)d_in[4];
  const float* wdense = (const float*)d_in[5];
  const float* bdense = (const float*)d_in[6];
  float* out = (float*)d_out;

  char* ws = (char*)d_ws;
  u16* W1 = (u16*)ws;                        // [12288][4096] bf16
  u16* X = (u16*)(ws + 134217728);           // [2048][4096] bf16
  u16* mixed = (u16*)(ws + 150994944);       // [2048][12288] bf16
  u16* ctx = (u16*)(ws + 201326592);         // [2048][4096] bf16
  float* cos_t = (float*)(ws + 218103808);
  float* sin_t = (float*)(ws + 218365952);

  // convert W1 + X only (W2 read as fp32 by gemmD); emit trig tables
  cvt3_kernel<<<dim3(2048), dim3(256), 0, stream>>>(
      wqkv, W1, N_QKV * KDIM / 4, hidden, X, S_LEN * HID / 4, cos_t, sin_t);

  // QKV: 256x384 tile -> 256 blocks = 1.00 exact round
  gemmQ<<<dim3(256), dim3(512), 0, stream>>>(X, W1, bqkv, mixed);

  // K-rope one-shot (Q-rope is fused in attention)
  ropek_kernel<<<dim3(4096), dim3(256), 0, stream>>>(mixed, pid, cos_t, sin_t);

  attn_kernel<<<dim3(512), dim3(256), 0, stream>>>(mixed, pid, cos_t, sin_t, ctx);

  // dense: fp32 W2 direct, 256 blocks = 1.00 exact round
  gemmD<<<dim3(256), dim3(512), 0, stream>>>(ctx, wdense, bdense, out);
}

// Round 12
// 484.938 us; speedup vs baseline: 1.0321x; 1.0165x over previous
//
#include <hip/hip_runtime.h>

typedef unsigned short u16;
typedef unsigned int u32;
typedef __attribute__((ext_vector_type(4))) float f32x4;
typedef __attribute__((ext_vector_type(16))) float f32x16;
typedef __attribute__((ext_vector_type(8))) short bf16x8;
typedef __attribute__((ext_vector_type(2))) unsigned int u32x2;

#define S_LEN 2048
#define NHEAD 32
#define HDD 128
#define HID 4096
#define N_QKV 12288
#define KDIM 4096
#define RS 12288  // mixed row stride (elements)

__device__ __forceinline__ u16 f2bf(float f) {
  u32 u = __builtin_bit_cast(u32, f);
  u = (u + 0x7FFFu + ((u >> 16) & 1u)) >> 16;
  return (u16)u;
}
__device__ __forceinline__ float bf2f(u16 h) {
  u32 u = ((u32)h) << 16;
  return __builtin_bit_cast(float, u);
}

__device__ __forceinline__ void gl2lds16(const void* g, void* l) {
  __builtin_amdgcn_global_load_lds(
      (const __attribute__((address_space(1))) u32*)g,
      (__attribute__((address_space(3))) u32*)l, 16, 0, 0);
}

#define FULL_BAR()                          \
  {                                         \
    asm volatile("" ::: "memory");          \
    __builtin_amdgcn_s_barrier();           \
    asm volatile("" ::: "memory");          \
  }

// ------ fused fp32 -> bf16 conversion (W1, X) + RoPE trig tables ----------
__global__ __launch_bounds__(256) void cvt3_kernel(const float* __restrict__ s0, u16* __restrict__ d0, int n0,
                                                   const float* __restrict__ s2, u16* __restrict__ d2, int n2,
                                                   float* __restrict__ cos_t, float* __restrict__ sin_t) {
  int i = blockIdx.x * blockDim.x + threadIdx.x;
  if (i < S_LEN * 32) {
    int s = i >> 5, ii = i & 31;
    float invf = expf(-0.28782313662425572f * (float)ii);
    float a = (float)s * invf;
    cos_t[i] = cosf(a);
    sin_t[i] = sinf(a);
  }
  int st = gridDim.x * blockDim.x;
  int ntot = n0 + n2;
  for (; i < ntot; i += st) {
    const float* s;
    u16* d;
    int j = i;
    if (j < n0) {
      s = s0; d = d0;
    } else {
      j -= n0; s = s2; d = d2;
    }
    float4 v = ((const float4*)s)[j];
    u32x2 o;
    o.x = (u32)f2bf(v.x) | ((u32)f2bf(v.y) << 16);
    o.y = (u32)f2bf(v.z) | ((u32)f2bf(v.w) << 16);
    ((u32x2*)d)[j] = o;
  }
}

// ---------------- standalone K-rope (K columns of mixed only) -------------
__global__ __launch_bounds__(256) void ropek_kernel(u16* __restrict__ mixed,
                                                    const int* __restrict__ pid,
                                                    const float* __restrict__ cos_t,
                                                    const float* __restrict__ sin_t) {
  int idx = blockIdx.x * blockDim.x + threadIdx.x;
  const int total = NHEAD * S_LEN * 2 * 8;  // 2^20
  if (idx >= total) return;
  int j = idx & 7;
  int half = (idx >> 3) & 1;
  int s = (idx >> 4) & (S_LEN - 1);
  int h = idx >> 15;
  int i0 = j * 4;
  int p = pid[half * S_LEN + s];
  float4 c4 = *(const float4*)(cos_t + p * 32 + i0);
  float4 s4 = *(const float4*)(sin_t + p * 32 + i0);
  u16* base = mixed + (size_t)s * RS + h * 384 + 128 + half * 64 + i0;
  ushort4 x1v = *(const ushort4*)(base);
  ushort4 x2v = *(const ushort4*)(base + 32);
  ushort4 o1, o2;
  {
    float x1 = bf2f(x1v.x), x2 = bf2f(x2v.x);
    o1.x = f2bf(x1 * c4.x - x2 * s4.x);
    o2.x = f2bf(x2 * c4.x + x1 * s4.x);
  }
  {
    float x1 = bf2f(x1v.y), x2 = bf2f(x2v.y);
    o1.y = f2bf(x1 * c4.y - x2 * s4.y);
    o2.y = f2bf(x2 * c4.y + x1 * s4.y);
  }
  {
    float x1 = bf2f(x1v.z), x2 = bf2f(x2v.z);
    o1.z = f2bf(x1 * c4.z - x2 * s4.z);
    o2.z = f2bf(x2 * c4.z + x1 * s4.z);
  }
  {
    float x1 = bf2f(x1v.w), x2 = bf2f(x2v.w);
    o1.w = f2bf(x1 * c4.w - x2 * s4.w);
    o2.w = f2bf(x2 * c4.w + x1 * s4.w);
  }
  *(ushort4*)(base) = o1;
  *(ushort4*)(base + 32) = o2;
}

// -------- QKV GEMM: 256x384 tile, BK=32, ring-3 LDS, 32x32x16 MFMA --------
// Same staging/schedule/swizzle as R10-R11 (43% MfmaUtil at 16x16); the
// MFMA shape moves the pipe ceiling 2075 -> 2382-2495 TF (m06/m119 +15-20%).
// Per-wave 128x96 = 4x3 tiles of 32x32, acc[4][3] f32x16 (192 acc regs).
// Per K-tile 24 MFMA: ph0 = kk0 (12 MFMA, 7 ds_reads), ph1 = kk1 (12, 7).
// A/B frag: row/col = lane&31, k = (lane>>5)*8 + i (generalizes the
// verified 16x16x32 mapping). C/D (m74/m101 verified): col = lane&31,
// row = (reg&3) + 8*(reg>>2) + 4*(lane>>5).
__global__ __launch_bounds__(512, 2) void gemmQ(const u16* __restrict__ A,
                                                const u16* __restrict__ B,
                                                const float* __restrict__ bias,
                                                u16* __restrict__ outb) {
  __shared__ __align__(16) char lds[3][40960];

  const int tid = threadIdx.x;
  const int lane = tid & 63, w = tid >> 6;
  const int l31 = lane & 31, hh = lane >> 5;
  const int wm = w >> 2, wn = w & 3;  // 2M x 4N

  int x = blockIdx.x & 7, loc = blockIdx.x >> 3;
  int mb = loc & 7, nb = x * 4 + (loc >> 3);
  const int bm = mb * 256, bn = nb * 384;

  f32x16 acc[4][3];
#pragma unroll
  for (int mi = 0; mi < 4; ++mi)
#pragma unroll
    for (int ni = 0; ni < 3; ++ni)
#pragma unroll
      for (int r = 0; r < 16; ++r) acc[mi][ni][r] = 0.f;

  const size_t K2 = (size_t)KDIM * 2;

  // A staging: 256 rows x 64B = 1024 slots, 2 loads/thread (inverse swizzle)
  const char* gA[2];
#pragma unroll
  for (int j = 0; j < 2; ++j) {
    int slot = j * 512 + tid;
    int line = slot >> 3;
    int sl = (slot & 7) ^ (line & 7);
    int row = 2 * line + (sl >> 2);
    int colb = (sl & 3) * 16;
    gA[j] = (const char*)A + (size_t)(bm + row) * K2 + colb;
  }
  // B staging: 384 rows x 64B = 1536 slots, 3 loads/thread
  const char* gB[3];
#pragma unroll
  for (int j = 0; j < 3; ++j) {
    int slot = j * 512 + tid;
    int line = slot >> 3;
    int sl = (slot & 7) ^ (line & 7);
    int row = 2 * line + (sl >> 2);
    int colb = (sl & 3) * 16;
    gB[j] = (const char*)B + (size_t)(bn + row) * K2 + colb;
  }
  const int ldst = w * 1024;

#define QIA(t, bi)                                                  \
  {                                                                 \
    char* Lb = lds[bi];                                             \
    gl2lds16(gA[0] + (size_t)(t) * 64, Lb + ldst);                  \
    gl2lds16(gA[1] + (size_t)(t) * 64, Lb + 8192 + ldst);           \
  }
#define QIB(t, bi)                                                  \
  {                                                                 \
    char* Lb = lds[bi] + 16384;                                     \
    _Pragma("unroll")                                               \
    for (int j = 0; j < 3; ++j)                                     \
      gl2lds16(gB[j] + (size_t)(t) * 64, Lb + j * 8192 + ldst);     \
  }

  // fragment ds_read byte offsets (paired-row swizzle), [idx][kk]
  // row = base + (lane&31); k16slot = kk*2 + (lane>>5)
  int offA[4][2], offB[3][2];
#pragma unroll
  for (int mi = 0; mi < 4; ++mi) {
    int r = wm * 128 + mi * 32 + l31;
    int line = r >> 1;
#pragma unroll
    for (int kk = 0; kk < 2; ++kk) {
      int sl = (((r & 1) << 2) + kk * 2 + hh) ^ (line & 7);
      offA[mi][kk] = line * 128 + sl * 16;
    }
  }
#pragma unroll
  for (int ni = 0; ni < 3; ++ni) {
    int r = wn * 96 + ni * 32 + l31;
    int line = r >> 1;
#pragma unroll
    for (int kk = 0; kk < 2; ++kk) {
      int sl = (((r & 1) << 2) + kk * 2 + hh) ^ (line & 7);
      offB[ni][kk] = 16384 + line * 128 + sl * 16;
    }
  }

  QIA(0, 0); QIB(0, 0);
  QIA(1, 1); QIB(1, 1);
  asm volatile("s_waitcnt vmcnt(5)" ::: "memory");
  FULL_BAR();

  int cur = 0, nx2 = 2;
  for (int kt = 0; kt < 128; ++kt) {
    const char* buf = lds[cur];
    const bool pf = (kt + 2) < 128;
    bf16x8 a[4], b[3];
    // ph0: kk0 frags (7 reads) | ISSUE A(kt+2) | BAR | 12 MFMA
#pragma unroll
    for (int mi = 0; mi < 4; ++mi) a[mi] = *(const bf16x8*)(buf + offA[mi][0]);
#pragma unroll
    for (int ni = 0; ni < 3; ++ni) b[ni] = *(const bf16x8*)(buf + offB[ni][0]);
    if (pf) QIA(kt + 2, nx2);
    FULL_BAR();
    __builtin_amdgcn_s_setprio(1);
#pragma unroll
    for (int mi = 0; mi < 4; ++mi)
#pragma unroll
      for (int ni = 0; ni < 3; ++ni)
        acc[mi][ni] = __builtin_amdgcn_mfma_f32_32x32x16_bf16(a[mi], b[ni], acc[mi][ni], 0, 0, 0);
    __builtin_amdgcn_s_setprio(0);
    // ph1: kk1 frags (7 reads) | ISSUE B(kt+2) | vmcnt(5) | BAR | 12 MFMA
#pragma unroll
    for (int mi = 0; mi < 4; ++mi) a[mi] = *(const bf16x8*)(buf + offA[mi][1]);
#pragma unroll
    for (int ni = 0; ni < 3; ++ni) b[ni] = *(const bf16x8*)(buf + offB[ni][1]);
    if (pf) {
      QIB(kt + 2, nx2);
      asm volatile("s_waitcnt vmcnt(5)" ::: "memory");
    } else if (kt == 126) {
      asm volatile("s_waitcnt vmcnt(0)" ::: "memory");
    }
    FULL_BAR();
    __builtin_amdgcn_s_setprio(1);
#pragma unroll
    for (int mi = 0; mi < 4; ++mi)
#pragma unroll
      for (int ni = 0; ni < 3; ++ni)
        acc[mi][ni] = __builtin_amdgcn_mfma_f32_32x32x16_bf16(a[mi], b[ni], acc[mi][ni], 0, 0, 0);
    __builtin_amdgcn_s_setprio(0);
    cur = (cur + 1 == 3) ? 0 : cur + 1;
    nx2 = (nx2 + 1 == 3) ? 0 : nx2 + 1;
  }
#undef QIA
#undef QIB

  // epilogue: 32x32 C/D layout — col = lane&31, row = (reg&3)+8*(reg>>2)+4*(lane>>5)
#pragma unroll
  for (int ni = 0; ni < 3; ++ni) {
    int n = bn + wn * 96 + ni * 32 + l31;
    float bv = bias[n];
#pragma unroll
    for (int mi = 0; mi < 4; ++mi) {
      int m0 = bm + wm * 128 + mi * 32 + 4 * hh;
#pragma unroll
      for (int reg = 0; reg < 16; ++reg) {
        int row = m0 + (reg & 3) + 8 * (reg >> 2);
        outb[(size_t)row * N_QKV + n] = f2bf(acc[mi][ni][reg] + bv);
      }
    }
  }
}

// -------- dense GEMM: 256x128, BK=64, A(bf16) gload_lds + B(fp32) reg-cvt --
// (unchanged from R11 for single-variable attribution)
__global__ __launch_bounds__(512, 2) void gemmD(const u16* __restrict__ A,
                                                const float* __restrict__ Bf,
                                                const float* __restrict__ bias,
                                                float* __restrict__ outf) {
  __shared__ __align__(16) char lds[2][49152];

  const int tid = threadIdx.x;
  const int lane = tid & 63, w = tid >> 6;
  const int l15 = lane & 15, g = lane >> 4;
  const int wm = w >> 1, wn = w & 1;  // 4M x 2N

  int x = blockIdx.x & 7, loc = blockIdx.x >> 3;
  int mb = loc & 7, nb = x * 4 + (loc >> 3);
  const int bm = mb * 256, bn = nb * 128;

  f32x4 acc[4][4];
  f32x4 z4 = {0.f, 0.f, 0.f, 0.f};
#pragma unroll
  for (int mi = 0; mi < 4; ++mi)
#pragma unroll
    for (int ni = 0; ni < 4; ++ni) acc[mi][ni] = z4;

  const size_t K2 = (size_t)KDIM * 2;

  const char* gA[2];
#pragma unroll
  for (int j = 0; j < 2; ++j) {
    int slot = j * 512 + tid;
    int line = slot >> 3;
    int sl = (slot & 7) ^ (line & 7);
    int row = 2 * line + (sl >> 2);
    int colb = (sl & 3) * 16;
    gA[j] = (const char*)A + (size_t)(bm + row) * K2 + colb;
  }
  int bline = tid >> 3;
  int bsl = tid & 7;
  int brow = 2 * bline + (bsl >> 2);
  int bcole = (bsl & 3) * 8;
  const float* gBs = Bf + (size_t)(bn + brow) * KDIM + bcole;
  int bphys = bsl ^ (bline & 7);
  const int bwr = 32768 + bline * 128 + bphys * 16;
  const int ldst = w * 1024;

#define DIA(t, kk)                                                            \
  {                                                                           \
    char* Lb = lds[(t) & 1] + (kk) * 16384;                                   \
    gl2lds16(gA[0] + (size_t)(t) * 128 + (kk) * 64, Lb + ldst);               \
    gl2lds16(gA[1] + (size_t)(t) * 128 + (kk) * 64, Lb + 8192 + ldst);        \
  }
#define DGB(t)                                                                \
  {                                                                           \
    const float* p0 = gBs + (size_t)(t) * 64;                                 \
    b0a = *(const float4*)(p0);                                               \
    b0b = *(const float4*)(p0 + 4);                                           \
    b1a = *(const float4*)(p0 + 32);                                          \
    b1b = *(const float4*)(p0 + 36);                                          \
  }
#define DWB(t)                                                                \
  {                                                                           \
    bf16x8 o0, o1;                                                            \
    o0[0] = (short)f2bf(b0a.x); o0[1] = (short)f2bf(b0a.y);                   \
    o0[2] = (short)f2bf(b0a.z); o0[3] = (short)f2bf(b0a.w);                   \
    o0[4] = (short)f2bf(b0b.x); o0[5] = (short)f2bf(b0b.y);                   \
    o0[6] = (short)f2bf(b0b.z); o0[7] = (short)f2bf(b0b.w);                   \
    o1[0] = (short)f2bf(b1a.x); o1[1] = (short)f2bf(b1a.y);                   \
    o1[2] = (short)f2bf(b1a.z); o1[3] = (short)f2bf(b1a.w);                   \
    o1[4] = (short)f2bf(b1b.x); o1[5] = (short)f2bf(b1b.y);                   \
    o1[6] = (short)f2bf(b1b.z); o1[7] = (short)f2bf(b1b.w);                   \
    char* Lb = lds[(t) & 1];                                                  \
    *(bf16x8*)(Lb + bwr) = o0;                                                \
    *(bf16x8*)(Lb + 8192 + bwr) = o1;                                         \
  }

  int offA[4], offB[2][4];
#pragma unroll
  for (int mi = 0; mi < 4; ++mi) {
    int r = wm * 64 + mi * 16 + l15;
    int line = r >> 1;
    int sl = (((r & 1) << 2) + g) ^ (line & 7);
    offA[mi] = line * 128 + sl * 16;
  }
#pragma unroll
  for (int kk = 0; kk < 2; ++kk)
#pragma unroll
    for (int ni = 0; ni < 4; ++ni) {
      int r = wn * 64 + ni * 16 + l15;
      int line = r >> 1;
      int sl = (((r & 1) << 2) + g) ^ (line & 7);
      offB[kk][ni] = 32768 + kk * 8192 + line * 128 + sl * 16;
    }

  float4 b0a, b0b, b1a, b1b;
  DGB(0);
  DIA(0, 0);
  DIA(0, 1);
  asm volatile("s_waitcnt vmcnt(4)" ::: "memory");
  DWB(0);
  asm volatile("s_waitcnt vmcnt(0) lgkmcnt(0)" ::: "memory");
  FULL_BAR();

  for (int kt = 0; kt < 64; ++kt) {
    const char* buf = lds[kt & 1];
    const bool pf = (kt + 1) < 64;
    bf16x8 a[4], b[4];
#pragma unroll
    for (int mi = 0; mi < 4; ++mi) a[mi] = *(const bf16x8*)(buf + offA[mi]);
#pragma unroll
    for (int ni = 0; ni < 4; ++ni) b[ni] = *(const bf16x8*)(buf + offB[0][ni]);
    if (pf) {
      DIA(kt + 1, 0);
      DGB(kt + 1);
      asm volatile("s_waitcnt vmcnt(6)" ::: "memory");
    } else {
      asm volatile("s_waitcnt vmcnt(0)" ::: "memory");
    }
    FULL_BAR();
    __builtin_amdgcn_s_setprio(1);
#pragma unroll
    for (int mi = 0; mi < 4; ++mi)
#pragma unroll
      for (int ni = 0; ni < 4; ++ni)
        acc[mi][ni] = __builtin_amdgcn_mfma_f32_16x16x32_bf16(a[mi], b[ni], acc[mi][ni], 0, 0, 0);
    __builtin_amdgcn_s_setprio(0);
#pragma unroll
    for (int mi = 0; mi < 4; ++mi) a[mi] = *(const bf16x8*)(buf + 16384 + offA[mi]);
#pragma unroll
    for (int ni = 0; ni < 4; ++ni) b[ni] = *(const bf16x8*)(buf + offB[1][ni]);
    if (pf) {
      DIA(kt + 1, 1);
      asm volatile("s_waitcnt vmcnt(2)" ::: "memory");
      DWB(kt + 1);
      asm volatile("s_waitcnt lgkmcnt(0)" ::: "memory");
    }
    FULL_BAR();
    __builtin_amdgcn_s_setprio(1);
#pragma unroll
    for (int mi = 0; mi < 4; ++mi)
#pragma unroll
      for (int ni = 0; ni < 4; ++ni)
        acc[mi][ni] = __builtin_amdgcn_mfma_f32_16x16x32_bf16(a[mi], b[ni], acc[mi][ni], 0, 0, 0);
    __builtin_amdgcn_s_setprio(0);
  }
#undef DIA
#undef DGB
#undef DWB

#pragma unroll
  for (int ni = 0; ni < 4; ++ni) {
    int n = bn + wn * 64 + ni * 16 + l15;
    float bv = bias[n];
#pragma unroll
    for (int mi = 0; mi < 4; ++mi) {
      int m0 = bm + wm * 64 + mi * 16 + 4 * g;
#pragma unroll
      for (int rr = 0; rr < 4; ++rr) outf[(size_t)(m0 + rr) * HID + n] = acc[mi][ni][rr] + bv;
    }
  }
}

// ------- flash attention, KVBLK=64, fused Q-rope, constant-work pairs -----
// (unchanged from R11)
__global__ __launch_bounds__(256) void attn_kernel(const u16* __restrict__ mixed,
                                                   const int* __restrict__ pid,
                                                   const float* __restrict__ cos_t,
                                                   const float* __restrict__ sin_t,
                                                   u16* __restrict__ ctx) {
  __shared__ __align__(16) u16 Ksh[64 * 136];
  __shared__ __align__(16) u16 Vsh[128 * 64];
  __shared__ __align__(16) u16 Pt[4][16 * 72];

  int tid = threadIdx.x;
  int lane = tid & 63, w = tid >> 6;
  int lane15 = lane & 15, g = lane >> 4;

  int bpair = blockIdx.x & 15;
  int h = blockIdx.x >> 4;

  const u16* qp = mixed + (size_t)h * 384;
  const u16* kp = mixed + (size_t)h * 384 + 128;
  const u16* vp = mixed + (size_t)h * 384 + 256;

  int krow = tid >> 2, kc = (tid & 3) * 32;
  int vk0 = 2 * (tid & 31), vd0 = (tid >> 5) * 16;
  f32x4 z4 = {0.f, 0.f, 0.f, 0.f};
  const float QSC = 0.08838834764831845f;
  const float L2E = 1.4426950408889634f;

  for (int pass = 0; pass < 2; ++pass) {
    int qi = pass ? (31 - bpair) : bpair;
    int qbase = qi * 64;
    int qrow = qbase + w * 16 + lane15;
    int ntiles = qi + 1;

    bf16x8 qf[4];
    const u16* qptr = qp + (size_t)qrow * RS + g * 8;
#pragma unroll
    for (int d0 = 0; d0 < 4; ++d0) qf[d0] = *(const bf16x8*)(qptr + d0 * 32);
    {
      int p1 = pid[qrow], p2 = pid[S_LEN + qrow];
      float cc[8], ss[8], dd[8], tt[8];
#pragma unroll
      for (int j = 0; j < 8; ++j) {
        cc[j] = cos_t[p1 * 32 + g * 8 + j];
        ss[j] = sin_t[p1 * 32 + g * 8 + j];
        dd[j] = cos_t[p2 * 32 + g * 8 + j];
        tt[j] = sin_t[p2 * 32 + g * 8 + j];
      }
#pragma unroll
      for (int j = 0; j < 8; ++j) {
        float x1 = bf2f((u16)qf[0][j]), x2 = bf2f((u16)qf[1][j]);
        qf[0][j] = (short)f2bf((x1 * cc[j] - x2 * ss[j]) * QSC);
        qf[1][j] = (short)f2bf((x2 * cc[j] + x1 * ss[j]) * QSC);
        float y1 = bf2f((u16)qf[2][j]), y2 = bf2f((u16)qf[3][j]);
        qf[2][j] = (short)f2bf((y1 * dd[j] - y2 * tt[j]) * QSC);
        qf[3][j] = (short)f2bf((y2 * dd[j] + y1 * tt[j]) * QSC);
      }
    }

    f32x4 pv[8];
#pragma unroll
    for (int db = 0; db < 8; ++db) pv[db] = z4;
    float m_run = -1e30f, l_run = 0.0f;

    for (int t = 0; t < ntiles; ++t) {
      int kb0 = t * 64;
      __syncthreads();
      {
        const bf16x8* src = (const bf16x8*)(kp + (size_t)(kb0 + krow) * RS + kc);
#pragma unroll
        for (int c = 0; c < 4; ++c)
          *(bf16x8*)(Ksh + krow * 136 + kc + c * 8) = src[c];
        const bf16x8* r0p = (const bf16x8*)(vp + (size_t)(kb0 + vk0) * RS + vd0);
        const bf16x8* r1p = (const bf16x8*)(vp + (size_t)(kb0 + vk0 + 1) * RS + vd0);
        bf16x8 r00 = r0p[0], r01 = r0p[1];
        bf16x8 r10 = r1p[0], r11 = r1p[1];
#pragma unroll
        for (int jj = 0; jj < 8; ++jj) {
          int d = vd0 + jj;
          u32 v0 = (u32)(u16)r00[jj] | ((u32)(u16)r10[jj] << 16);
          *(u32*)((char*)Vsh + d * 128 + (((vk0 >> 3) ^ (d & 7)) << 4) + (vk0 & 7) * 2) = v0;
          int d2 = vd0 + 8 + jj;
          u32 v1 = (u32)(u16)r01[jj] | ((u32)(u16)r11[jj] << 16);
          *(u32*)((char*)Vsh + d2 * 128 + (((vk0 >> 3) ^ (d2 & 7)) << 4) + (vk0 & 7) * 2) = v1;
        }
      }
      __syncthreads();

      f32x4 sa[4];
#pragma unroll
      for (int kt16 = 0; kt16 < 4; ++kt16) sa[kt16] = z4;
#pragma unroll
      for (int kt16 = 0; kt16 < 4; ++kt16)
#pragma unroll
        for (int d0 = 0; d0 < 4; ++d0) {
          bf16x8 kf = *(const bf16x8*)(Ksh + (kt16 * 16 + lane15) * 136 + d0 * 32 + g * 8);
          sa[kt16] = __builtin_amdgcn_mfma_f32_16x16x32_bf16(kf, qf[d0], sa[kt16], 0, 0, 0);
        }
      float s[16];
#pragma unroll
      for (int kt16 = 0; kt16 < 4; ++kt16)
#pragma unroll
        for (int rr = 0; rr < 4; ++rr) {
          int kg = kb0 + kt16 * 16 + 4 * g + rr;
          s[kt16 * 4 + rr] = (kg > qrow) ? -1e30f : sa[kt16][rr];
        }
      float mx = s[0];
#pragma unroll
      for (int i2 = 1; i2 < 16; ++i2) mx = fmaxf(mx, s[i2]);
      mx = fmaxf(mx, __shfl_xor(mx, 16));
      mx = fmaxf(mx, __shfl_xor(mx, 32));
      float mnew = fmaxf(m_run, mx);
      float fac = exp2f((m_run - mnew) * L2E);
      float p[16], psum = 0.f;
#pragma unroll
      for (int i2 = 0; i2 < 16; ++i2) {
        p[i2] = exp2f((s[i2] - mnew) * L2E);
        psum += p[i2];
      }
      psum += __shfl_xor(psum, 16);
      psum += __shfl_xor(psum, 32);
      l_run = l_run * fac + psum;
      m_run = mnew;
#pragma unroll
      for (int db = 0; db < 8; ++db) pv[db] *= fac;

#pragma unroll
      for (int kt16 = 0; kt16 < 4; ++kt16) {
        u32x2 pw;
        pw.x = (u32)f2bf(p[kt16 * 4 + 0]) | ((u32)f2bf(p[kt16 * 4 + 1]) << 16);
        pw.y = (u32)f2bf(p[kt16 * 4 + 2]) | ((u32)f2bf(p[kt16 * 4 + 3]) << 16);
        *(u32x2*)(&Pt[w][lane15 * 72 + kt16 * 16 + 4 * g]) = pw;
      }
      asm volatile("s_waitcnt lgkmcnt(0)" ::: "memory");
      bf16x8 pf0 = *(const bf16x8*)(&Pt[w][lane15 * 72 + 8 * g]);
      bf16x8 pf1 = *(const bf16x8*)(&Pt[w][lane15 * 72 + 32 + 8 * g]);

#pragma unroll
      for (int db = 0; db < 8; ++db) {
        int d = db * 16 + lane15;
        bf16x8 vf0 = *(const bf16x8*)((const char*)Vsh + d * 128 + ((g ^ (d & 7)) << 4));
        bf16x8 vf1 = *(const bf16x8*)((const char*)Vsh + d * 128 + (((4 + g) ^ (d & 7)) << 4));
        pv[db] = __builtin_amdgcn_mfma_f32_16x16x32_bf16(vf0, pf0, pv[db], 0, 0, 0);
        pv[db] = __builtin_amdgcn_mfma_f32_16x16x32_bf16(vf1, pf1, pv[db], 0, 0, 0);
      }
    }

    float inv = 1.0f / l_run;
#pragma unroll
    for (int db = 0; db < 8; ++db) {
      ushort4 o;
      o.x = f2bf(pv[db][0] * inv);
      o.y = f2bf(pv[db][1] * inv);
      o.z = f2bf(pv[db][2] * inv);
      o.w = f2bf(pv[db][3] * inv);
      *(ushort4*)(ctx + (size_t)qrow * HID + h * HDD + db * 16 + 4 * g) = o;
    }
    __syncthreads();
  }
}

// ---------------- launcher -------------------------------------------------
extern "C" void kernel_launch(void* const* d_in, const int* in_sizes, int n_in,
                              void* d_out, int out_size, void* d_ws, size_t ws_size,
                              hipStream_t stream) {
  const float* hidden = (const float*)d_in[0];
  const int* pid = (const int*)d_in[1];
  const float* wqkv = (const float*)d_in[3];
  const float* bqkv = (const float*)d_in[4];
  const float* wdense = (const float*)d_in[5];
  const float* bdense = (const float*)d_in[6];
  float* out = (float*)d_out;

  char* ws = (char*)d_ws;
  u16* W1 = (u16*)ws;                        // [12288][4096] bf16
  u16* X = (u16*)(ws + 134217728);           // [2048][4096] bf16
  u16* mixed = (u16*)(ws + 150994944);       // [2048][12288] bf16
  u16* ctx = (u16*)(ws + 201326592);         // [2048][4096] bf16
  float* cos_t = (float*)(ws + 218103808);
  float* sin_t = (float*)(ws + 218365952);

  cvt3_kernel<<<dim3(2048), dim3(256), 0, stream>>>(
      wqkv, W1, N_QKV * KDIM / 4, hidden, X, S_LEN * HID / 4, cos_t, sin_t);

  // QKV: 256x384 tile -> 256 blocks = 1.00 exact round, 32x32x16 MFMA
  gemmQ<<<dim3(256), dim3(512), 0, stream>>>(X, W1, bqkv, mixed);

  ropek_kernel<<<dim3(4096), dim3(256), 0, stream>>>(mixed, pid, cos_t, sin_t);

  attn_kernel<<<dim3(512), dim3(256), 0, stream>>>(mixed, pid, cos_t, sin_t, ctx);

  gemmD<<<dim3(256), dim3(512), 0, stream>>>(ctx, wdense, bdense, out);
}

// Round 13
// 483.118 us; speedup vs baseline: 1.0360x; 1.0038x over previous
//
#include <hip/hip_runtime.h>

typedef unsigned short u16;
typedef unsigned int u32;
typedef __attribute__((ext_vector_type(4))) float f32x4;
typedef __attribute__((ext_vector_type(16))) float f32x16;
typedef __attribute__((ext_vector_type(8))) short bf16x8;
typedef __attribute__((ext_vector_type(2))) unsigned int u32x2;

#define S_LEN 2048
#define NHEAD 32
#define HDD 128
#define HID 4096
#define N_QKV 12288
#define KDIM 4096
#define RS 12288  // mixed row stride (elements)

__device__ __forceinline__ u16 f2bf(float f) {
  u32 u = __builtin_bit_cast(u32, f);
  u = (u + 0x7FFFu + ((u >> 16) & 1u)) >> 16;
  return (u16)u;
}
__device__ __forceinline__ float bf2f(u16 h) {
  u32 u = ((u32)h) << 16;
  return __builtin_bit_cast(float, u);
}

// Gray-key slot swizzle: key has period 32 in row (line = row>>1), so any
// two rows 8/16/24 apart land on different 16B bank-slots. Involution.
__device__ __forceinline__ int gkey(int line) { return (line ^ (line >> 1)) & 7; }

__device__ __forceinline__ void gl2lds16(const void* g, void* l) {
  __builtin_amdgcn_global_load_lds(
      (const __attribute__((address_space(1))) u32*)g,
      (__attribute__((address_space(3))) u32*)l, 16, 0, 0);
}

#define FULL_BAR()                          \
  {                                         \
    asm volatile("" ::: "memory");          \
    __builtin_amdgcn_s_barrier();           \
    asm volatile("" ::: "memory");          \
  }

// ------ fused fp32 -> bf16 conversion (W1, X) + RoPE trig tables ----------
__global__ __launch_bounds__(256) void cvt3_kernel(const float* __restrict__ s0, u16* __restrict__ d0, int n0,
                                                   const float* __restrict__ s2, u16* __restrict__ d2, int n2,
                                                   float* __restrict__ cos_t, float* __restrict__ sin_t) {
  int i = blockIdx.x * blockDim.x + threadIdx.x;
  if (i < S_LEN * 32) {
    int s = i >> 5, ii = i & 31;
    float invf = expf(-0.28782313662425572f * (float)ii);
    float a = (float)s * invf;
    cos_t[i] = cosf(a);
    sin_t[i] = sinf(a);
  }
  int st = gridDim.x * blockDim.x;
  int ntot = n0 + n2;
  for (; i < ntot; i += st) {
    const float* s;
    u16* d;
    int j = i;
    if (j < n0) {
      s = s0; d = d0;
    } else {
      j -= n0; s = s2; d = d2;
    }
    float4 v = ((const float4*)s)[j];
    u32x2 o;
    o.x = (u32)f2bf(v.x) | ((u32)f2bf(v.y) << 16);
    o.y = (u32)f2bf(v.z) | ((u32)f2bf(v.w) << 16);
    ((u32x2*)d)[j] = o;
  }
}

// ---------------- standalone K-rope (K columns of mixed only) -------------
__global__ __launch_bounds__(256) void ropek_kernel(u16* __restrict__ mixed,
                                                    const int* __restrict__ pid,
                                                    const float* __restrict__ cos_t,
                                                    const float* __restrict__ sin_t) {
  int idx = blockIdx.x * blockDim.x + threadIdx.x;
  const int total = NHEAD * S_LEN * 2 * 8;  // 2^20
  if (idx >= total) return;
  int j = idx & 7;
  int half = (idx >> 3) & 1;
  int s = (idx >> 4) & (S_LEN - 1);
  int h = idx >> 15;
  int i0 = j * 4;
  int p = pid[half * S_LEN + s];
  float4 c4 = *(const float4*)(cos_t + p * 32 + i0);
  float4 s4 = *(const float4*)(sin_t + p * 32 + i0);
  u16* base = mixed + (size_t)s * RS + h * 384 + 128 + half * 64 + i0;
  ushort4 x1v = *(const ushort4*)(base);
  ushort4 x2v = *(const ushort4*)(base + 32);
  ushort4 o1, o2;
  {
    float x1 = bf2f(x1v.x), x2 = bf2f(x2v.x);
    o1.x = f2bf(x1 * c4.x - x2 * s4.x);
    o2.x = f2bf(x2 * c4.x + x1 * s4.x);
  }
  {
    float x1 = bf2f(x1v.y), x2 = bf2f(x2v.y);
    o1.y = f2bf(x1 * c4.y - x2 * s4.y);
    o2.y = f2bf(x2 * c4.y + x1 * s4.y);
  }
  {
    float x1 = bf2f(x1v.z), x2 = bf2f(x2v.z);
    o1.z = f2bf(x1 * c4.z - x2 * s4.z);
    o2.z = f2bf(x2 * c4.z + x1 * s4.z);
  }
  {
    float x1 = bf2f(x1v.w), x2 = bf2f(x2v.w);
    o1.w = f2bf(x1 * c4.w - x2 * s4.w);
    o2.w = f2bf(x2 * c4.w + x1 * s4.w);
  }
  *(ushort4*)(base) = o1;
  *(ushort4*)(base + 32) = o2;
}

// -------- QKV GEMM: 256x384, BK=32, ring-3, 32x32x16 MFMA, Gray-key -------
__global__ __launch_bounds__(512, 2) void gemmQ(const u16* __restrict__ A,
                                                const u16* __restrict__ B,
                                                const float* __restrict__ bias,
                                                u16* __restrict__ outb) {
  __shared__ __align__(16) char lds[3][40960];

  const int tid = threadIdx.x;
  const int lane = tid & 63, w = tid >> 6;
  const int l31 = lane & 31, hh = lane >> 5;
  const int wm = w >> 2, wn = w & 3;  // 2M x 4N

  int x = blockIdx.x & 7, loc = blockIdx.x >> 3;
  int mb = loc & 7, nb = x * 4 + (loc >> 3);
  const int bm = mb * 256, bn = nb * 384;

  f32x16 acc[4][3];
#pragma unroll
  for (int mi = 0; mi < 4; ++mi)
#pragma unroll
    for (int ni = 0; ni < 3; ++ni)
#pragma unroll
      for (int r = 0; r < 16; ++r) acc[mi][ni][r] = 0.f;

  const size_t K2 = (size_t)KDIM * 2;

  // A staging: 1024 slots, 2 loads/thread (inverse Gray-key swizzle)
  const char* gA[2];
#pragma unroll
  for (int j = 0; j < 2; ++j) {
    int slot = j * 512 + tid;
    int line = slot >> 3;
    int sl = (slot & 7) ^ gkey(line);
    int row = 2 * line + (sl >> 2);
    int colb = (sl & 3) * 16;
    gA[j] = (const char*)A + (size_t)(bm + row) * K2 + colb;
  }
  // B staging: 1536 slots, 3 loads/thread
  const char* gB[3];
#pragma unroll
  for (int j = 0; j < 3; ++j) {
    int slot = j * 512 + tid;
    int line = slot >> 3;
    int sl = (slot & 7) ^ gkey(line);
    int row = 2 * line + (sl >> 2);
    int colb = (sl & 3) * 16;
    gB[j] = (const char*)B + (size_t)(bn + row) * K2 + colb;
  }
  const int ldst = w * 1024;

#define QIA(t, bi)                                                  \
  {                                                                 \
    char* Lb = lds[bi];                                             \
    gl2lds16(gA[0] + (size_t)(t) * 64, Lb + ldst);                  \
    gl2lds16(gA[1] + (size_t)(t) * 64, Lb + 8192 + ldst);           \
  }
#define QIB(t, bi)                                                  \
  {                                                                 \
    char* Lb = lds[bi] + 16384;                                     \
    _Pragma("unroll")                                               \
    for (int j = 0; j < 3; ++j)                                     \
      gl2lds16(gB[j] + (size_t)(t) * 64, Lb + j * 8192 + ldst);     \
  }

  // fragment ds_read byte offsets (Gray-key), [idx][kk]
  int offA[4][2], offB[3][2];
#pragma unroll
  for (int mi = 0; mi < 4; ++mi) {
    int r = wm * 128 + mi * 32 + l31;
    int line = r >> 1;
#pragma unroll
    for (int kk = 0; kk < 2; ++kk) {
      int sl = (((r & 1) << 2) + kk * 2 + hh) ^ gkey(line);
      offA[mi][kk] = line * 128 + sl * 16;
    }
  }
#pragma unroll
  for (int ni = 0; ni < 3; ++ni) {
    int r = wn * 96 + ni * 32 + l31;
    int line = r >> 1;
#pragma unroll
    for (int kk = 0; kk < 2; ++kk) {
      int sl = (((r & 1) << 2) + kk * 2 + hh) ^ gkey(line);
      offB[ni][kk] = 16384 + line * 128 + sl * 16;
    }
  }

  QIA(0, 0); QIB(0, 0);
  QIA(1, 1); QIB(1, 1);
  asm volatile("s_waitcnt vmcnt(5)" ::: "memory");
  FULL_BAR();

  int cur = 0, nx2 = 2;
  for (int kt = 0; kt < 128; ++kt) {
    const char* buf = lds[cur];
    const bool pf = (kt + 2) < 128;
    bf16x8 a[4], b[3];
    // ph0: kk0 frags | ISSUE A(kt+2) | BAR | 12 MFMA
#pragma unroll
    for (int mi = 0; mi < 4; ++mi) a[mi] = *(const bf16x8*)(buf + offA[mi][0]);
#pragma unroll
    for (int ni = 0; ni < 3; ++ni) b[ni] = *(const bf16x8*)(buf + offB[ni][0]);
    if (pf) QIA(kt + 2, nx2);
    FULL_BAR();
    __builtin_amdgcn_s_setprio(1);
#pragma unroll
    for (int mi = 0; mi < 4; ++mi)
#pragma unroll
      for (int ni = 0; ni < 3; ++ni)
        acc[mi][ni] = __builtin_amdgcn_mfma_f32_32x32x16_bf16(a[mi], b[ni], acc[mi][ni], 0, 0, 0);
    __builtin_amdgcn_s_setprio(0);
    // ph1: kk1 frags | ISSUE B(kt+2) | vmcnt(5) | BAR | 12 MFMA
#pragma unroll
    for (int mi = 0; mi < 4; ++mi) a[mi] = *(const bf16x8*)(buf + offA[mi][1]);
#pragma unroll
    for (int ni = 0; ni < 3; ++ni) b[ni] = *(const bf16x8*)(buf + offB[ni][1]);
    if (pf) {
      QIB(kt + 2, nx2);
      asm volatile("s_waitcnt vmcnt(5)" ::: "memory");
    } else if (kt == 126) {
      asm volatile("s_waitcnt vmcnt(0)" ::: "memory");
    }
    FULL_BAR();
    __builtin_amdgcn_s_setprio(1);
#pragma unroll
    for (int mi = 0; mi < 4; ++mi)
#pragma unroll
      for (int ni = 0; ni < 3; ++ni)
        acc[mi][ni] = __builtin_amdgcn_mfma_f32_32x32x16_bf16(a[mi], b[ni], acc[mi][ni], 0, 0, 0);
    __builtin_amdgcn_s_setprio(0);
    cur = (cur + 1 == 3) ? 0 : cur + 1;
    nx2 = (nx2 + 1 == 3) ? 0 : nx2 + 1;
  }
#undef QIA
#undef QIB

  // epilogue: 32x32 C/D — col = lane&31, row = (reg&3)+8*(reg>>2)+4*hh
#pragma unroll
  for (int ni = 0; ni < 3; ++ni) {
    int n = bn + wn * 96 + ni * 32 + l31;
    float bv = bias[n];
#pragma unroll
    for (int mi = 0; mi < 4; ++mi) {
      int m0 = bm + wm * 128 + mi * 32 + 4 * hh;
#pragma unroll
      for (int reg = 0; reg < 16; ++reg) {
        int row = m0 + (reg & 3) + 8 * (reg >> 2);
        outb[(size_t)row * N_QKV + n] = f2bf(acc[mi][ni][reg] + bv);
      }
    }
  }
}

// -------- dense GEMM: 256x128, BK=64, 32x32x16 MFMA, Gray-key -------------
// A(bf16) gload_lds; B(fp32 W2) reg-staged + converted in-kernel.
// 8 waves (4M x 2N), per-wave 64x64 = acc[2][2] f32x16. Same vmcnt ledger
// as R11/R12: ph0 vmcnt(6) certifies A(t,1); ph1 vmcnt(2) certifies
// A(t+1,0)+B-regs; queue never <2 mid-loop.
__global__ __launch_bounds__(512, 2) void gemmD(const u16* __restrict__ A,
                                                const float* __restrict__ Bf,
                                                const float* __restrict__ bias,
                                                float* __restrict__ outf) {
  __shared__ __align__(16) char lds[2][49152];

  const int tid = threadIdx.x;
  const int lane = tid & 63, w = tid >> 6;
  const int l31 = lane & 31, hh = lane >> 5;
  const int wm = w >> 1, wn = w & 1;  // 4M x 2N

  int x = blockIdx.x & 7, loc = blockIdx.x >> 3;
  int mb = loc & 7, nb = x * 4 + (loc >> 3);
  const int bm = mb * 256, bn = nb * 128;

  f32x16 acc[2][2];
#pragma unroll
  for (int mi = 0; mi < 2; ++mi)
#pragma unroll
    for (int ni = 0; ni < 2; ++ni)
#pragma unroll
      for (int r = 0; r < 16; ++r) acc[mi][ni][r] = 0.f;

  const size_t K2 = (size_t)KDIM * 2;

  // A staging (per kk unit: 256 rows x 64B, Gray-key, 2 glds)
  const char* gA[2];
#pragma unroll
  for (int j = 0; j < 2; ++j) {
    int slot = j * 512 + tid;
    int line = slot >> 3;
    int sl = (slot & 7) ^ gkey(line);
    int row = 2 * line + (sl >> 2);
    int colb = (sl & 3) * 16;
    gA[j] = (const char*)A + (size_t)(bm + row) * K2 + colb;
  }
  // B reg-staging: thread covers logical slot tid in BOTH kk subunits.
  int bline = tid >> 3;
  int bsl = tid & 7;
  int brow = 2 * bline + (bsl >> 2);
  int bcole = (bsl & 3) * 8;
  const float* gBs = Bf + (size_t)(bn + brow) * KDIM + bcole;
  int bphys = bsl ^ gkey(bline);
  const int bwr = 32768 + bline * 128 + bphys * 16;
  const int ldst = w * 1024;

#define DIA(t, kk)                                                            \
  {                                                                           \
    char* Lb = lds[(t) & 1] + (kk) * 16384;                                   \
    gl2lds16(gA[0] + (size_t)(t) * 128 + (kk) * 64, Lb + ldst);               \
    gl2lds16(gA[1] + (size_t)(t) * 128 + (kk) * 64, Lb + 8192 + ldst);        \
  }
#define DGB(t)                                                                \
  {                                                                           \
    const float* p0 = gBs + (size_t)(t) * 64;                                 \
    b0a = *(const float4*)(p0);                                               \
    b0b = *(const float4*)(p0 + 4);                                           \
    b1a = *(const float4*)(p0 + 32);                                          \
    b1b = *(const float4*)(p0 + 36);                                          \
  }
#define DWB(t)                                                                \
  {                                                                           \
    bf16x8 o0, o1;                                                            \
    o0[0] = (short)f2bf(b0a.x); o0[1] = (short)f2bf(b0a.y);                   \
    o0[2] = (short)f2bf(b0a.z); o0[3] = (short)f2bf(b0a.w);                   \
    o0[4] = (short)f2bf(b0b.x); o0[5] = (short)f2bf(b0b.y);                   \
    o0[6] = (short)f2bf(b0b.z); o0[7] = (short)f2bf(b0b.w);                   \
    o1[0] = (short)f2bf(b1a.x); o1[1] = (short)f2bf(b1a.y);                   \
    o1[2] = (short)f2bf(b1a.z); o1[3] = (short)f2bf(b1a.w);                   \
    o1[4] = (short)f2bf(b1b.x); o1[5] = (short)f2bf(b1b.y);                   \
    o1[6] = (short)f2bf(b1b.z); o1[7] = (short)f2bf(b1b.w);                   \
    char* Lb = lds[(t) & 1];                                                  \
    *(bf16x8*)(Lb + bwr) = o0;                                                \
    *(bf16x8*)(Lb + 8192 + bwr) = o1;                                         \
  }

  // fragment offsets: [mi/ni][kk-unit][step], Gray-key
  int offA[2][2][2], offB[2][2][2];
#pragma unroll
  for (int mi = 0; mi < 2; ++mi) {
    int r = wm * 64 + mi * 32 + l31;
    int line = r >> 1;
#pragma unroll
    for (int kku = 0; kku < 2; ++kku)
#pragma unroll
      for (int st = 0; st < 2; ++st) {
        int sl = (((r & 1) << 2) + st * 2 + hh) ^ gkey(line);
        offA[mi][kku][st] = kku * 16384 + line * 128 + sl * 16;
      }
  }
#pragma unroll
  for (int ni = 0; ni < 2; ++ni) {
    int r = wn * 64 + ni * 32 + l31;
    int line = r >> 1;
#pragma unroll
    for (int kku = 0; kku < 2; ++kku)
#pragma unroll
      for (int st = 0; st < 2; ++st) {
        int sl = (((r & 1) << 2) + st * 2 + hh) ^ gkey(line);
        offB[ni][kku][st] = 32768 + kku * 8192 + line * 128 + sl * 16;
      }
  }

  float4 b0a, b0b, b1a, b1b;
  DGB(0);
  DIA(0, 0);
  DIA(0, 1);
  asm volatile("s_waitcnt vmcnt(4)" ::: "memory");
  DWB(0);
  asm volatile("s_waitcnt vmcnt(0) lgkmcnt(0)" ::: "memory");
  FULL_BAR();

  for (int kt = 0; kt < 64; ++kt) {
    const char* buf = lds[kt & 1];
    const bool pf = (kt + 1) < 64;
    bf16x8 a[2][2], b[2][2];
    // ph0: kk-unit 0
#pragma unroll
    for (int mi = 0; mi < 2; ++mi)
#pragma unroll
      for (int st = 0; st < 2; ++st) a[mi][st] = *(const bf16x8*)(buf + offA[mi][0][st]);
#pragma unroll
    for (int ni = 0; ni < 2; ++ni)
#pragma unroll
      for (int st = 0; st < 2; ++st) b[ni][st] = *(const bf16x8*)(buf + offB[ni][0][st]);
    if (pf) {
      DIA(kt + 1, 0);
      DGB(kt + 1);
      asm volatile("s_waitcnt vmcnt(6)" ::: "memory");
    } else {
      asm volatile("s_waitcnt vmcnt(0)" ::: "memory");
    }
    FULL_BAR();
    __builtin_amdgcn_s_setprio(1);
#pragma unroll
    for (int st = 0; st < 2; ++st)
#pragma unroll
      for (int mi = 0; mi < 2; ++mi)
#pragma unroll
        for (int ni = 0; ni < 2; ++ni)
          acc[mi][ni] = __builtin_amdgcn_mfma_f32_32x32x16_bf16(a[mi][st], b[ni][st], acc[mi][ni], 0, 0, 0);
    __builtin_amdgcn_s_setprio(0);
    // ph1: kk-unit 1
#pragma unroll
    for (int mi = 0; mi < 2; ++mi)
#pragma unroll
      for (int st = 0; st < 2; ++st) a[mi][st] = *(const bf16x8*)(buf + offA[mi][1][st]);
#pragma unroll
    for (int ni = 0; ni < 2; ++ni)
#pragma unroll
      for (int st = 0; st < 2; ++st) b[ni][st] = *(const bf16x8*)(buf + offB[ni][1][st]);
    if (pf) {
      DIA(kt + 1, 1);
      asm volatile("s_waitcnt vmcnt(2)" ::: "memory");
      DWB(kt + 1);
      asm volatile("s_waitcnt lgkmcnt(0)" ::: "memory");
    }
    FULL_BAR();
    __builtin_amdgcn_s_setprio(1);
#pragma unroll
    for (int st = 0; st < 2; ++st)
#pragma unroll
      for (int mi = 0; mi < 2; ++mi)
#pragma unroll
        for (int ni = 0; ni < 2; ++ni)
          acc[mi][ni] = __builtin_amdgcn_mfma_f32_32x32x16_bf16(a[mi][st], b[ni][st], acc[mi][ni], 0, 0, 0);
    __builtin_amdgcn_s_setprio(0);
  }
#undef DIA
#undef DGB
#undef DWB

  // epilogue: 32x32 C/D layout, f32 out + bias
#pragma unroll
  for (int ni = 0; ni < 2; ++ni) {
    int n = bn + wn * 64 + ni * 32 + l31;
    float bv = bias[n];
#pragma unroll
    for (int mi = 0; mi < 2; ++mi) {
      int m0 = bm + wm * 64 + mi * 32 + 4 * hh;
#pragma unroll
      for (int reg = 0; reg < 16; ++reg) {
        int row = m0 + (reg & 3) + 8 * (reg >> 2);
        outf[(size_t)row * HID + n] = acc[mi][ni][reg] + bv;
      }
    }
  }
}

// ------- flash attention, KVBLK=64, fused Q-rope, constant-work pairs -----
// (unchanged from R12)
__global__ __launch_bounds__(256) void attn_kernel(const u16* __restrict__ mixed,
                                                   const int* __restrict__ pid,
                                                   const float* __restrict__ cos_t,
                                                   const float* __restrict__ sin_t,
                                                   u16* __restrict__ ctx) {
  __shared__ __align__(16) u16 Ksh[64 * 136];
  __shared__ __align__(16) u16 Vsh[128 * 64];
  __shared__ __align__(16) u16 Pt[4][16 * 72];

  int tid = threadIdx.x;
  int lane = tid & 63, w = tid >> 6;
  int lane15 = lane & 15, g = lane >> 4;

  int bpair = blockIdx.x & 15;
  int h = blockIdx.x >> 4;

  const u16* qp = mixed + (size_t)h * 384;
  const u16* kp = mixed + (size_t)h * 384 + 128;
  const u16* vp = mixed + (size_t)h * 384 + 256;

  int krow = tid >> 2, kc = (tid & 3) * 32;
  int vk0 = 2 * (tid & 31), vd0 = (tid >> 5) * 16;
  f32x4 z4 = {0.f, 0.f, 0.f, 0.f};
  const float QSC = 0.08838834764831845f;
  const float L2E = 1.4426950408889634f;

  for (int pass = 0; pass < 2; ++pass) {
    int qi = pass ? (31 - bpair) : bpair;
    int qbase = qi * 64;
    int qrow = qbase + w * 16 + lane15;
    int ntiles = qi + 1;

    bf16x8 qf[4];
    const u16* qptr = qp + (size_t)qrow * RS + g * 8;
#pragma unroll
    for (int d0 = 0; d0 < 4; ++d0) qf[d0] = *(const bf16x8*)(qptr + d0 * 32);
    {
      int p1 = pid[qrow], p2 = pid[S_LEN + qrow];
      float cc[8], ss[8], dd[8], tt[8];
#pragma unroll
      for (int j = 0; j < 8; ++j) {
        cc[j] = cos_t[p1 * 32 + g * 8 + j];
        ss[j] = sin_t[p1 * 32 + g * 8 + j];
        dd[j] = cos_t[p2 * 32 + g * 8 + j];
        tt[j] = sin_t[p2 * 32 + g * 8 + j];
      }
#pragma unroll
      for (int j = 0; j < 8; ++j) {
        float x1 = bf2f((u16)qf[0][j]), x2 = bf2f((u16)qf[1][j]);
        qf[0][j] = (short)f2bf((x1 * cc[j] - x2 * ss[j]) * QSC);
        qf[1][j] = (short)f2bf((x2 * cc[j] + x1 * ss[j]) * QSC);
        float y1 = bf2f((u16)qf[2][j]), y2 = bf2f((u16)qf[3][j]);
        qf[2][j] = (short)f2bf((y1 * dd[j] - y2 * tt[j]) * QSC);
        qf[3][j] = (short)f2bf((y2 * dd[j] + y1 * tt[j]) * QSC);
      }
    }

    f32x4 pv[8];
#pragma unroll
    for (int db = 0; db < 8; ++db) pv[db] = z4;
    float m_run = -1e30f, l_run = 0.0f;

    for (int t = 0; t < ntiles; ++t) {
      int kb0 = t * 64;
      __syncthreads();
      {
        const bf16x8* src = (const bf16x8*)(kp + (size_t)(kb0 + krow) * RS + kc);
#pragma unroll
        for (int c = 0; c < 4; ++c)
          *(bf16x8*)(Ksh + krow * 136 + kc + c * 8) = src[c];
        const bf16x8* r0p = (const bf16x8*)(vp + (size_t)(kb0 + vk0) * RS + vd0);
        const bf16x8* r1p = (const bf16x8*)(vp + (size_t)(kb0 + vk0 + 1) * RS + vd0);
        bf16x8 r00 = r0p[0], r01 = r0p[1];
        bf16x8 r10 = r1p[0], r11 = r1p[1];
#pragma unroll
        for (int jj = 0; jj < 8; ++jj) {
          int d = vd0 + jj;
          u32 v0 = (u32)(u16)r00[jj] | ((u32)(u16)r10[jj] << 16);
          *(u32*)((char*)Vsh + d * 128 + (((vk0 >> 3) ^ (d & 7)) << 4) + (vk0 & 7) * 2) = v0;
          int d2 = vd0 + 8 + jj;
          u32 v1 = (u32)(u16)r01[jj] | ((u32)(u16)r11[jj] << 16);
          *(u32*)((char*)Vsh + d2 * 128 + (((vk0 >> 3) ^ (d2 & 7)) << 4) + (vk0 & 7) * 2) = v1;
        }
      }
      __syncthreads();

      f32x4 sa[4];
#pragma unroll
      for (int kt16 = 0; kt16 < 4; ++kt16) sa[kt16] = z4;
#pragma unroll
      for (int kt16 = 0; kt16 < 4; ++kt16)
#pragma unroll
        for (int d0 = 0; d0 < 4; ++d0) {
          bf16x8 kf = *(const bf16x8*)(Ksh + (kt16 * 16 + lane15) * 136 + d0 * 32 + g * 8);
          sa[kt16] = __builtin_amdgcn_mfma_f32_16x16x32_bf16(kf, qf[d0], sa[kt16], 0, 0, 0);
        }
      float s[16];
#pragma unroll
      for (int kt16 = 0; kt16 < 4; ++kt16)
#pragma unroll
        for (int rr = 0; rr < 4; ++rr) {
          int kg = kb0 + kt16 * 16 + 4 * g + rr;
          s[kt16 * 4 + rr] = (kg > qrow) ? -1e30f : sa[kt16][rr];
        }
      float mx = s[0];
#pragma unroll
      for (int i2 = 1; i2 < 16; ++i2) mx = fmaxf(mx, s[i2]);
      mx = fmaxf(mx, __shfl_xor(mx, 16));
      mx = fmaxf(mx, __shfl_xor(mx, 32));
      float mnew = fmaxf(m_run, mx);
      float fac = exp2f((m_run - mnew) * L2E);
      float p[16], psum = 0.f;
#pragma unroll
      for (int i2 = 0; i2 < 16; ++i2) {
        p[i2] = exp2f((s[i2] - mnew) * L2E);
        psum += p[i2];
      }
      psum += __shfl_xor(psum, 16);
      psum += __shfl_xor(psum, 32);
      l_run = l_run * fac + psum;
      m_run = mnew;
#pragma unroll
      for (int db = 0; db < 8; ++db) pv[db] *= fac;

#pragma unroll
      for (int kt16 = 0; kt16 < 4; ++kt16) {
        u32x2 pw;
        pw.x = (u32)f2bf(p[kt16 * 4 + 0]) | ((u32)f2bf(p[kt16 * 4 + 1]) << 16);
        pw.y = (u32)f2bf(p[kt16 * 4 + 2]) | ((u32)f2bf(p[kt16 * 4 + 3]) << 16);
        *(u32x2*)(&Pt[w][lane15 * 72 + kt16 * 16 + 4 * g]) = pw;
      }
      asm volatile("s_waitcnt lgkmcnt(0)" ::: "memory");
      bf16x8 pf0 = *(const bf16x8*)(&Pt[w][lane15 * 72 + 8 * g]);
      bf16x8 pf1 = *(const bf16x8*)(&Pt[w][lane15 * 72 + 32 + 8 * g]);

#pragma unroll
      for (int db = 0; db < 8; ++db) {
        int d = db * 16 + lane15;
        bf16x8 vf0 = *(const bf16x8*)((const char*)Vsh + d * 128 + ((g ^ (d & 7)) << 4));
        bf16x8 vf1 = *(const bf16x8*)((const char*)Vsh + d * 128 + (((4 + g) ^ (d & 7)) << 4));
        pv[db] = __builtin_amdgcn_mfma_f32_16x16x32_bf16(vf0, pf0, pv[db], 0, 0, 0);
        pv[db] = __builtin_amdgcn_mfma_f32_16x16x32_bf16(vf1, pf1, pv[db], 0, 0, 0);
      }
    }

    float inv = 1.0f / l_run;
#pragma unroll
    for (int db = 0; db < 8; ++db) {
      ushort4 o;
      o.x = f2bf(pv[db][0] * inv);
      o.y = f2bf(pv[db][1] * inv);
      o.z = f2bf(pv[db][2] * inv);
      o.w = f2bf(pv[db][3] * inv);
      *(ushort4*)(ctx + (size_t)qrow * HID + h * HDD + db * 16 + 4 * g) = o;
    }
    __syncthreads();
  }
}

// ---------------- launcher -------------------------------------------------
extern "C" void kernel_launch(void* const* d_in, const int* in_sizes, int n_in,
                              void* d_out, int out_size, void* d_ws, size_t ws_size,
                              hipStream_t stream) {
  const float* hidden = (const float*)d_in[0];
  const int* pid = (const int*)d_in[1];
  const float* wqkv = (const float*)d_in[3];
  const float* bqkv = (const float*)d_in[4];
  const float* wdense = (const float*)d_in[5];
  const float* bdense = (const float*)d_in[6];
  float* out = (float*)d_out;

  char* ws = (char*)d_ws;
  u16* W1 = (u16*)ws;                        // [12288][4096] bf16
  u16* X = (u16*)(ws + 134217728);           // [2048][4096] bf16
  u16* mixed = (u16*)(ws + 150994944);       // [2048][12288] bf16
  u16* ctx = (u16*)(ws + 201326592);         // [2048][4096] bf16
  float* cos_t = (float*)(ws + 218103808);
  float* sin_t = (float*)(ws + 218365952);

  cvt3_kernel<<<dim3(2048), dim3(256), 0, stream>>>(
      wqkv, W1, N_QKV * KDIM / 4, hidden, X, S_LEN * HID / 4, cos_t, sin_t);

  gemmQ<<<dim3(256), dim3(512), 0, stream>>>(X, W1, bqkv, mixed);

  ropek_kernel<<<dim3(4096), dim3(256), 0, stream>>>(mixed, pid, cos_t, sin_t);

  attn_kernel<<<dim3(512), dim3(256), 0, stream>>>(mixed, pid, cos_t, sin_t, ctx);

  gemmD<<<dim3(256), dim3(512), 0, stream>>>(ctx, wdense, bdense, out);
}